// Round 1
// baseline (658.460 us; speedup 1.0000x reference)
//
#include <hip/hip_runtime.h>

#define N_NODES 100000
#define N_EDGES 600000
#define F 128
#define OUTD 64

// ---------------- CSR build ----------------
__global__ __launch_bounds__(256) void k_zero(int* __restrict__ a, int* __restrict__ b) {
    int i = blockIdx.x * blockDim.x + threadIdx.x;
    if (i < N_NODES) { a[i] = 0; b[i] = 0; }
}

__global__ __launch_bounds__(256) void k_hist(const int* __restrict__ dst, int* __restrict__ deg) {
    int e = blockIdx.x * blockDim.x + threadIdx.x;
    if (e < N_EDGES) atomicAdd(&deg[dst[e]], 1);
}

// scan phase 1: blocks of 1024 elements (256 thr x 4), inclusive per-block scan
__global__ __launch_bounds__(256) void k_scan1(const int* __restrict__ deg, int* __restrict__ row_ptr,
                                               int* __restrict__ blksum) {
    __shared__ int sm[256];
    int t = threadIdx.x, b = blockIdx.x;
    int base = b * 1024 + t * 4;
    int v[4];
    int run = 0;
#pragma unroll
    for (int i = 0; i < 4; i++) {
        int idx = base + i;
        int d = (idx < N_NODES) ? deg[idx] : 0;
        run += d;
        v[i] = run;
    }
    sm[t] = run;
    __syncthreads();
    for (int off = 1; off < 256; off <<= 1) {
        int add = 0;
        if (t >= off) add = sm[t - off];
        __syncthreads();
        sm[t] += add;
        __syncthreads();
    }
    int excl = sm[t] - run;
#pragma unroll
    for (int i = 0; i < 4; i++) {
        int idx = base + i;
        if (idx < N_NODES) row_ptr[idx + 1] = excl + v[i];
    }
    if (t == 255) blksum[b] = sm[255];
}

__global__ __launch_bounds__(128) void k_scan2(int* __restrict__ blksum, int nblk) {
    __shared__ int sm[128];
    int t = threadIdx.x;
    int v = (t < nblk) ? blksum[t] : 0;
    sm[t] = v;
    __syncthreads();
    for (int off = 1; off < 128; off <<= 1) {
        int add = 0;
        if (t >= off) add = sm[t - off];
        __syncthreads();
        sm[t] += add;
        __syncthreads();
    }
    if (t < nblk) blksum[t] = sm[t] - v;  // exclusive
}

__global__ __launch_bounds__(256) void k_scan3(const int* __restrict__ deg, int* __restrict__ row_ptr,
                                               const int* __restrict__ blksum, float* __restrict__ inv_deg) {
    int i = blockIdx.x * blockDim.x + threadIdx.x;
    if (i == 0) row_ptr[0] = 0;
    if (i < N_NODES) {
        row_ptr[i + 1] += blksum[i >> 10];
        int d = deg[i];
        inv_deg[i] = 1.0f / (float)(d > 0 ? d : 1);
    }
}

__global__ __launch_bounds__(256) void k_fill(const int* __restrict__ src, const int* __restrict__ dst,
                                              const int* __restrict__ row_ptr, int* __restrict__ cnt,
                                              int* __restrict__ col) {
    int e = blockIdx.x * blockDim.x + threadIdx.x;
    if (e < N_EDGES) {
        int d = dst[e];
        int p = row_ptr[d] + atomicAdd(&cnt[d], 1);
        col[p] = src[e];
    }
}

// ---------------- aggregation: one wave per node, mean of neighbor rows ----------------
__global__ __launch_bounds__(256) void k_agg(const float* __restrict__ h, const int* __restrict__ row_ptr,
                                             const int* __restrict__ col, const float* __restrict__ inv_deg,
                                             float* __restrict__ out) {
    int gtid = blockIdx.x * blockDim.x + threadIdx.x;
    int node = gtid >> 6;
    int lane = threadIdx.x & 63;
    if (node >= N_NODES) return;
    int s = row_ptr[node], e = row_ptr[node + 1];
    float2 acc = make_float2(0.f, 0.f);
    const float2* hp = (const float2*)h;
    for (int p = s; p < e; ++p) {
        int c = col[p];
        float2 v = hp[(size_t)c * 64 + lane];
        acc.x += v.x;
        acc.y += v.y;
    }
    float iv = inv_deg[node];
    float2 o = make_float2(acc.x * iv, acc.y * iv);
    ((float2*)out)[(size_t)node * 64 + lane] = o;
}

// ---------------- fused dual GEMM: out = act(h@Ws + hn@Wn + bs + bn) ----------------
// BM=64 nodes, BN=128 cols, K=256 (128 self || 128 neigh), KC=32, 256 threads, 4x8 per thread
template <int RELU>
__global__ __launch_bounds__(256) void k_gemm(const float* __restrict__ h, const float* __restrict__ hn,
                                              const float* __restrict__ Ws, const float* __restrict__ Wn,
                                              const float* __restrict__ bs, const float* __restrict__ bn,
                                              float* __restrict__ out) {
    __shared__ float As[64][36];
    __shared__ float Bs[32][132];
    const int tid = threadIdx.x;
    const int m0 = blockIdx.x * 64;
    const int tm = tid >> 4;  // 0..15 (4 nodes each)
    const int tn = tid & 15;  // 0..15 (8 cols each)

    float acc[4][8];
#pragma unroll
    for (int i = 0; i < 4; i++)
#pragma unroll
        for (int j = 0; j < 8; j++) acc[i][j] = 0.f;

    float bias[8];
#pragma unroll
    for (int j = 0; j < 8; j++) bias[j] = bs[tn * 8 + j] + bn[tn * 8 + j];

    const int ar = tid >> 3;        // 0..31
    const int ac = (tid & 7) * 4;   // 0..28
    const int br0 = tid >> 5;       // 0..7
    const int bc = (tid & 31) * 4;  // 0..124

    for (int kc = 0; kc < 8; ++kc) {
        const float* Asrc = (kc < 4) ? h : hn;
        const float* Bsrc = (kc < 4) ? Ws : Wn;
        const int koff = (kc & 3) * 32;
#pragma unroll
        for (int r = ar; r < 64; r += 32) {
            int row = m0 + r;
            if (row >= N_NODES) row = N_NODES - 1;
            float4 v = *(const float4*)&Asrc[(size_t)row * 128 + koff + ac];
            *(float4*)&As[r][ac] = v;
        }
#pragma unroll
        for (int rr = br0; rr < 32; rr += 8) {
            float4 v = *(const float4*)&Bsrc[(size_t)(koff + rr) * 128 + bc];
            *(float4*)&Bs[rr][bc] = v;
        }
        __syncthreads();
#pragma unroll
        for (int kk = 0; kk < 32; ++kk) {
            float a[4];
#pragma unroll
            for (int i = 0; i < 4; i++) a[i] = As[tm * 4 + i][kk];
            float4 b0 = *(const float4*)&Bs[kk][tn * 8];
            float4 b1 = *(const float4*)&Bs[kk][tn * 8 + 4];
            float b[8] = {b0.x, b0.y, b0.z, b0.w, b1.x, b1.y, b1.z, b1.w};
#pragma unroll
            for (int i = 0; i < 4; i++)
#pragma unroll
                for (int j = 0; j < 8; j++) acc[i][j] = fmaf(a[i], b[j], acc[i][j]);
        }
        __syncthreads();
    }
#pragma unroll
    for (int i = 0; i < 4; i++) {
        int row = m0 + tm * 4 + i;
        if (row < N_NODES) {
            float v[8];
#pragma unroll
            for (int j = 0; j < 8; j++) {
                v[j] = acc[i][j] + bias[j];
                if (RELU) v[j] = fmaxf(v[j], 0.f);
            }
            float4 o0 = make_float4(v[0], v[1], v[2], v[3]);
            float4 o1 = make_float4(v[4], v[5], v[6], v[7]);
            *(float4*)&out[(size_t)row * 128 + tn * 8] = o0;
            *(float4*)&out[(size_t)row * 128 + tn * 8 + 4] = o1;
        }
    }
}

// ---------------- final linear: out = h @ W_out + b_out (128 -> 64) ----------------
// BM=64, BN=64, K=128, KC=32, 256 threads, 4x4 per thread
__global__ __launch_bounds__(256) void k_final(const float* __restrict__ h, const float* __restrict__ W,
                                               const float* __restrict__ b, float* __restrict__ out) {
    __shared__ float As[64][36];
    __shared__ float Bs[32][68];
    const int tid = threadIdx.x;
    const int m0 = blockIdx.x * 64;
    const int tm = tid >> 4;  // 0..15 (4 nodes)
    const int tn = tid & 15;  // 0..15 (4 cols)

    float acc[4][4];
#pragma unroll
    for (int i = 0; i < 4; i++)
#pragma unroll
        for (int j = 0; j < 4; j++) acc[i][j] = 0.f;

    float bias[4];
#pragma unroll
    for (int j = 0; j < 4; j++) bias[j] = b[tn * 4 + j];

    const int ar = tid >> 3;       // 0..31
    const int ac = (tid & 7) * 4;  // 0..28
    const int br0 = tid >> 4;      // 0..15
    const int bc = (tid & 15) * 4; // 0..60

    for (int kc = 0; kc < 4; ++kc) {
        const int koff = kc * 32;
#pragma unroll
        for (int r = ar; r < 64; r += 32) {
            int row = m0 + r;
            if (row >= N_NODES) row = N_NODES - 1;
            float4 v = *(const float4*)&h[(size_t)row * 128 + koff + ac];
            *(float4*)&As[r][ac] = v;
        }
#pragma unroll
        for (int rr = br0; rr < 32; rr += 16) {
            float4 v = *(const float4*)&W[(size_t)(koff + rr) * 64 + bc];
            *(float4*)&Bs[rr][bc] = v;
        }
        __syncthreads();
#pragma unroll
        for (int kk = 0; kk < 32; ++kk) {
            float a[4];
#pragma unroll
            for (int i = 0; i < 4; i++) a[i] = As[tm * 4 + i][kk];
            float4 bv = *(const float4*)&Bs[kk][tn * 4];
            float bb[4] = {bv.x, bv.y, bv.z, bv.w};
#pragma unroll
            for (int i = 0; i < 4; i++)
#pragma unroll
                for (int j = 0; j < 4; j++) acc[i][j] = fmaf(a[i], bb[j], acc[i][j]);
        }
        __syncthreads();
    }
#pragma unroll
    for (int i = 0; i < 4; i++) {
        int row = m0 + tm * 4 + i;
        if (row < N_NODES) {
            float4 o = make_float4(acc[i][0] + bias[0], acc[i][1] + bias[1],
                                   acc[i][2] + bias[2], acc[i][3] + bias[3]);
            *(float4*)&out[(size_t)row * 64 + tn * 4] = o;
        }
    }
}

extern "C" void kernel_launch(void* const* d_in, const int* in_sizes, int n_in,
                              void* d_out, int out_size, void* d_ws, size_t ws_size,
                              hipStream_t stream) {
    const float* feat = (const float*)d_in[0];
    const int* src = (const int*)d_in[1];
    const int* dst = (const int*)d_in[2];
    const float* Ws[3] = {(const float*)d_in[3], (const float*)d_in[7], (const float*)d_in[11]};
    const float* bsv[3] = {(const float*)d_in[4], (const float*)d_in[8], (const float*)d_in[12]};
    const float* Wn[3] = {(const float*)d_in[5], (const float*)d_in[9], (const float*)d_in[13]};
    const float* bnv[3] = {(const float*)d_in[6], (const float*)d_in[10], (const float*)d_in[14]};
    const float* Wo = (const float*)d_in[15];
    const float* bo = (const float*)d_in[16];
    float* out = (float*)d_out;

    char* ws = (char*)d_ws;
    const size_t HBYTES = (size_t)N_NODES * F * 4;  // 51.2 MB
    float* hA = (float*)ws;
    float* hB = (float*)(ws + HBYTES);
    float* agg = (float*)(ws + 2 * HBYTES);
    char* p = ws + 3 * HBYTES;
    int* deg = (int*)p;            p += (size_t)N_NODES * 4;
    float* inv = (float*)p;        p += (size_t)N_NODES * 4;
    int* rp = (int*)p;             p += (size_t)(N_NODES + 1) * 4 + 252;  // keep alignment
    int* cnt = (int*)p;            p += (size_t)N_NODES * 4;
    int* col = (int*)p;            p += (size_t)N_EDGES * 4;
    int* blksum = (int*)p;

    const int nScanBlk = (N_NODES + 1023) / 1024;  // 98
    const int edgeBlk = (N_EDGES + 255) / 256;
    const int nodeBlk = (N_NODES + 255) / 256;

    k_zero<<<nodeBlk, 256, 0, stream>>>(deg, cnt);
    k_hist<<<edgeBlk, 256, 0, stream>>>(dst, deg);
    k_scan1<<<nScanBlk, 256, 0, stream>>>(deg, rp, blksum);
    k_scan2<<<1, 128, 0, stream>>>(blksum, nScanBlk);
    k_scan3<<<nodeBlk, 256, 0, stream>>>(deg, rp, blksum, inv);
    k_fill<<<edgeBlk, 256, 0, stream>>>(src, dst, rp, cnt, col);

    const int aggBlk = (N_NODES * 64 + 255) / 256;  // 25000
    const int gemmBlk = (N_NODES + 63) / 64;        // 1563

    // layer 0
    k_agg<<<aggBlk, 256, 0, stream>>>(feat, rp, col, inv, agg);
    k_gemm<1><<<gemmBlk, 256, 0, stream>>>(feat, agg, Ws[0], Wn[0], bsv[0], bnv[0], hA);
    // layer 1
    k_agg<<<aggBlk, 256, 0, stream>>>(hA, rp, col, inv, agg);
    k_gemm<1><<<gemmBlk, 256, 0, stream>>>(hA, agg, Ws[1], Wn[1], bsv[1], bnv[1], hB);
    // layer 2
    k_agg<<<aggBlk, 256, 0, stream>>>(hB, rp, col, inv, agg);
    k_gemm<0><<<gemmBlk, 256, 0, stream>>>(hB, agg, Ws[2], Wn[2], bsv[2], bnv[2], hA);
    // final linear
    k_final<<<gemmBlk, 256, 0, stream>>>(hA, Wo, bo, out);
}

// Round 2
// 363.519 us; speedup vs baseline: 1.8114x; 1.8114x over previous
//
#include <hip/hip_runtime.h>

#define N_NODES 100000
#define N_EDGES 600000
#define F 128
#define OUTD 64

typedef short bf16x8 __attribute__((ext_vector_type(8)));
typedef float f32x4 __attribute__((ext_vector_type(4)));

__device__ __forceinline__ unsigned short f2bf(float f) {
    union { float f; unsigned u; } v; v.f = f;
    unsigned u = v.u;
    return (unsigned short)((u + 0x7FFFu + ((u >> 16) & 1u)) >> 16);
}
__device__ __forceinline__ float bf2f(unsigned short s) {
    union { unsigned u; float f; } v; v.u = ((unsigned)s) << 16;
    return v.f;
}

__device__ __forceinline__ void async_copy16(void* lds, const void* g) {
    __builtin_amdgcn_global_load_lds((const __attribute__((address_space(1))) void*)g,
                                     (__attribute__((address_space(3))) void*)lds, 16, 0, 0);
}

// ---------------- feature convert fp32 -> bf16 ----------------
__global__ __launch_bounds__(256) void k_cvt(const float4* __restrict__ in, ushort* __restrict__ out) {
    int i = blockIdx.x * blockDim.x + threadIdx.x;  // 3.2M float4
    float4 v = in[i];
    ushort4 o;
    o.x = f2bf(v.x); o.y = f2bf(v.y); o.z = f2bf(v.z); o.w = f2bf(v.w);
    *(ushort4*)&out[i * 4] = o;
}

// ---------------- weight transpose+convert: Wt[n][k] = bf16(W[k][n]) ----------------
__global__ __launch_bounds__(128) void k_wt(const float* __restrict__ w0, const float* __restrict__ w1,
                                            const float* __restrict__ w2, const float* __restrict__ w3,
                                            const float* __restrict__ w4, const float* __restrict__ w5,
                                            ushort* __restrict__ wt) {
    int which = blockIdx.y;
    const float* s = w0;
    if (which == 1) s = w1; else if (which == 2) s = w2; else if (which == 3) s = w3;
    else if (which == 4) s = w4; else if (which == 5) s = w5;
    int n = blockIdx.x, k = threadIdx.x;
    wt[which * 16384 + n * 128 + k] = f2bf(s[k * 128 + n]);
}

__global__ __launch_bounds__(128) void k_wto(const float* __restrict__ w, ushort* __restrict__ wt) {
    int n = blockIdx.x, k = threadIdx.x;
    wt[n * 128 + k] = f2bf(w[k * 64 + n]);
}

// ---------------- CSR build ----------------
__global__ __launch_bounds__(256) void k_zero(int* __restrict__ a, int* __restrict__ b) {
    int i = blockIdx.x * blockDim.x + threadIdx.x;
    if (i < N_NODES) { a[i] = 0; b[i] = 0; }
}

__global__ __launch_bounds__(256) void k_hist(const int* __restrict__ dst, int* __restrict__ deg) {
    int e = blockIdx.x * blockDim.x + threadIdx.x;
    if (e < N_EDGES) atomicAdd(&deg[dst[e]], 1);
}

__global__ __launch_bounds__(256) void k_scan1(const int* __restrict__ deg, int* __restrict__ row_ptr,
                                               int* __restrict__ blksum) {
    __shared__ int sm[256];
    int t = threadIdx.x, b = blockIdx.x;
    int base = b * 1024 + t * 4;
    int v[4];
    int run = 0;
#pragma unroll
    for (int i = 0; i < 4; i++) {
        int idx = base + i;
        int d = (idx < N_NODES) ? deg[idx] : 0;
        run += d;
        v[i] = run;
    }
    sm[t] = run;
    __syncthreads();
    for (int off = 1; off < 256; off <<= 1) {
        int add = 0;
        if (t >= off) add = sm[t - off];
        __syncthreads();
        sm[t] += add;
        __syncthreads();
    }
    int excl = sm[t] - run;
#pragma unroll
    for (int i = 0; i < 4; i++) {
        int idx = base + i;
        if (idx < N_NODES) row_ptr[idx + 1] = excl + v[i];
    }
    if (t == 255) blksum[b] = sm[255];
}

__global__ __launch_bounds__(128) void k_scan2(int* __restrict__ blksum, int nblk) {
    __shared__ int sm[128];
    int t = threadIdx.x;
    int v = (t < nblk) ? blksum[t] : 0;
    sm[t] = v;
    __syncthreads();
    for (int off = 1; off < 128; off <<= 1) {
        int add = 0;
        if (t >= off) add = sm[t - off];
        __syncthreads();
        sm[t] += add;
        __syncthreads();
    }
    if (t < nblk) blksum[t] = sm[t] - v;  // exclusive
}

__global__ __launch_bounds__(256) void k_scan3(const int* __restrict__ deg, int* __restrict__ row_ptr,
                                               const int* __restrict__ blksum, float* __restrict__ inv_deg) {
    int i = blockIdx.x * blockDim.x + threadIdx.x;
    if (i == 0) row_ptr[0] = 0;
    if (i < N_NODES) {
        row_ptr[i + 1] += blksum[i >> 10];
        int d = deg[i];
        inv_deg[i] = 1.0f / (float)(d > 0 ? d : 1);
    }
}

__global__ __launch_bounds__(256) void k_fill(const int* __restrict__ src, const int* __restrict__ dst,
                                              const int* __restrict__ row_ptr, int* __restrict__ cnt,
                                              int* __restrict__ col) {
    int e = blockIdx.x * blockDim.x + threadIdx.x;
    if (e < N_EDGES) {
        int d = dst[e];
        int p = row_ptr[d] + atomicAdd(&cnt[d], 1);
        col[p] = src[e];
    }
}

// ---------------- aggregation (bf16 h): one wave per node ----------------
__global__ __launch_bounds__(256) void k_agg(const ushort* __restrict__ h, const int* __restrict__ row_ptr,
                                             const int* __restrict__ col, const float* __restrict__ inv_deg,
                                             ushort* __restrict__ out) {
    int gtid = blockIdx.x * blockDim.x + threadIdx.x;
    int node = gtid >> 6;
    int lane = threadIdx.x & 63;
    if (node >= N_NODES) return;
    int s = row_ptr[node], e = row_ptr[node + 1];
    float ax = 0.f, ay = 0.f;
    const unsigned* hp = (const unsigned*)h;  // 2 bf16 per lane
    for (int p = s; p < e; ++p) {
        int c = col[p];
        unsigned v = hp[(size_t)c * 64 + lane];
        ax += bf2f((unsigned short)(v & 0xFFFF));
        ay += bf2f((unsigned short)(v >> 16));
    }
    float iv = inv_deg[node];
    unsigned o = (unsigned)f2bf(ax * iv) | ((unsigned)f2bf(ay * iv) << 16);
    ((unsigned*)out)[(size_t)node * 64 + lane] = o;
}

// ---------------- MFMA fused dual GEMM: out = act(h@Ws + hn@Wn + bs + bn) ----------------
// BM=128, BN=128, K=256 (h||hn), BK=32. 4 waves in 2x2, each 64x64 (4x4 frags of 16x16x32).
template <int RELU>
__global__ __launch_bounds__(256) void k_gemm(const ushort* __restrict__ h, const ushort* __restrict__ hn,
                                              const ushort* __restrict__ Wts, const ushort* __restrict__ Wtn,
                                              const float* __restrict__ bs, const float* __restrict__ bn,
                                              ushort* __restrict__ out) {
    __shared__ ushort smem[16384];  // 32KB: staging As[128][32] + Bs[128][32]; epilogue cbuf
    ushort* As = smem;          // 4096 shorts
    ushort* Bs = smem + 4096;   // 4096 shorts
    const int t = threadIdx.x;
    const int w = t >> 6, l = t & 63;
    const int wr = w >> 1, wc = w & 1;
    const int m0 = blockIdx.x * 128;

    f32x4 acc[4][4];
#pragma unroll
    for (int m = 0; m < 4; m++)
#pragma unroll
        for (int n = 0; n < 4; n++) acc[m][n] = (f32x4){0.f, 0.f, 0.f, 0.f};

    const int arow = t >> 2;          // 0..63
    const int acolsh = (t & 3) * 8;   // short offset within 32-k row

    for (int kt = 0; kt < 8; ++kt) {
        const ushort* Asrc = (kt < 4) ? h : hn;
        const ushort* Bsrc = (kt < 4) ? Wts : Wtn;
        const int koff = (kt & 3) * 32;
#pragma unroll
        for (int i = 0; i < 2; ++i) {
            int row = m0 + i * 64 + arow;
            if (row > N_NODES - 1) row = N_NODES - 1;
            async_copy16(As + i * 2048 + w * 512, Asrc + (size_t)row * 128 + koff + acolsh);
            async_copy16(Bs + i * 2048 + w * 512, Bsrc + (size_t)(i * 64 + arow) * 128 + koff + acolsh);
        }
        __syncthreads();
        const int kcol = (l >> 4) * 8;
        bf16x8 aF[4], bF[4];
#pragma unroll
        for (int m = 0; m < 4; m++) aF[m] = *(const bf16x8*)&As[(wr * 64 + m * 16 + (l & 15)) * 32 + kcol];
#pragma unroll
        for (int n = 0; n < 4; n++) bF[n] = *(const bf16x8*)&Bs[(wc * 64 + n * 16 + (l & 15)) * 32 + kcol];
#pragma unroll
        for (int m = 0; m < 4; m++)
#pragma unroll
            for (int n = 0; n < 4; n++)
                acc[m][n] = __builtin_amdgcn_mfma_f32_16x16x32_bf16(aF[m], bF[n], acc[m][n], 0, 0, 0);
        __syncthreads();
    }

    // epilogue: bias+act, stage through per-wave LDS tile for coalesced bf16 stores
    float bias[4];
#pragma unroll
    for (int n = 0; n < 4; n++) {
        int gc = wc * 64 + n * 16 + (l & 15);
        bias[n] = bs[gc] + bn[gc];
    }
    ushort* cw = smem + w * 4096;  // [64][64] bf16 per wave
#pragma unroll
    for (int m = 0; m < 4; m++)
#pragma unroll
        for (int n = 0; n < 4; n++) {
            int lr0 = m * 16 + (l >> 4) * 4;
            int lc = n * 16 + (l & 15);
#pragma unroll
            for (int j = 0; j < 4; j++) {
                float v = acc[m][n][j] + bias[n];
                if (RELU) v = fmaxf(v, 0.f);
                cw[(lr0 + j) * 64 + lc] = f2bf(v);
            }
        }
    // same-wave read-back (no barrier needed), coalesced 16B stores
#pragma unroll
    for (int r = 0; r < 8; r++) {
        int row = r * 8 + (l >> 3);
        int cs = (l & 7) * 8;
        bf16x8 vv = *(const bf16x8*)&cw[row * 64 + cs];
        int grow = m0 + wr * 64 + row;
        if (grow < N_NODES) *(bf16x8*)&out[(size_t)grow * 128 + wc * 64 + cs] = vv;
    }
}

// ---------------- final linear MFMA: out(fp32) = h @ W_out + b_out ----------------
// BM=128, BN=64, K=128, BK=32. 4 waves 2x2, each 64x32 (4x2 frags).
__global__ __launch_bounds__(256) void k_final(const ushort* __restrict__ h, const ushort* __restrict__ Wto,
                                               const float* __restrict__ bo, float* __restrict__ out) {
    __shared__ ushort smem[16384];
    ushort* As = smem;         // [128][32]
    ushort* Bs = smem + 4096;  // [64][32]
    const int t = threadIdx.x;
    const int w = t >> 6, l = t & 63;
    const int wr = w >> 1, wc = w & 1;
    const int m0 = blockIdx.x * 128;

    f32x4 acc[4][2];
#pragma unroll
    for (int m = 0; m < 4; m++)
#pragma unroll
        for (int n = 0; n < 2; n++) acc[m][n] = (f32x4){0.f, 0.f, 0.f, 0.f};

    const int arow = t >> 2;
    const int acolsh = (t & 3) * 8;

    for (int kt = 0; kt < 4; ++kt) {
        const int koff = kt * 32;
#pragma unroll
        for (int i = 0; i < 2; ++i) {
            int row = m0 + i * 64 + arow;
            if (row > N_NODES - 1) row = N_NODES - 1;
            async_copy16(As + i * 2048 + w * 512, h + (size_t)row * 128 + koff + acolsh);
        }
        async_copy16(Bs + w * 512, Wto + (size_t)arow * 128 + koff + acolsh);
        __syncthreads();
        const int kcol = (l >> 4) * 8;
        bf16x8 aF[4], bF[2];
#pragma unroll
        for (int m = 0; m < 4; m++) aF[m] = *(const bf16x8*)&As[(wr * 64 + m * 16 + (l & 15)) * 32 + kcol];
#pragma unroll
        for (int n = 0; n < 2; n++) bF[n] = *(const bf16x8*)&Bs[(wc * 32 + n * 16 + (l & 15)) * 32 + kcol];
#pragma unroll
        for (int m = 0; m < 4; m++)
#pragma unroll
            for (int n = 0; n < 2; n++)
                acc[m][n] = __builtin_amdgcn_mfma_f32_16x16x32_bf16(aF[m], bF[n], acc[m][n], 0, 0, 0);
        __syncthreads();
    }

    float bias[2];
#pragma unroll
    for (int n = 0; n < 2; n++) bias[n] = bo[wc * 32 + n * 16 + (l & 15)];

    float* cw = (float*)smem + w * 2048;  // [64][32] fp32 per wave
#pragma unroll
    for (int m = 0; m < 4; m++)
#pragma unroll
        for (int n = 0; n < 2; n++) {
            int lr0 = m * 16 + (l >> 4) * 4;
            int lc = n * 16 + (l & 15);
#pragma unroll
            for (int j = 0; j < 4; j++) cw[(lr0 + j) * 32 + lc] = acc[m][n][j] + bias[n];
        }
#pragma unroll
    for (int r = 0; r < 8; r++) {
        int row = r * 8 + (l >> 3);
        int cf = (l & 7) * 4;
        float4 vv = *(const float4*)&cw[row * 32 + cf];
        int grow = m0 + wr * 64 + row;
        if (grow < N_NODES) *(float4*)&out[(size_t)grow * 64 + wc * 32 + cf] = vv;
    }
}

extern "C" void kernel_launch(void* const* d_in, const int* in_sizes, int n_in,
                              void* d_out, int out_size, void* d_ws, size_t ws_size,
                              hipStream_t stream) {
    const float* feat = (const float*)d_in[0];
    const int* src = (const int*)d_in[1];
    const int* dst = (const int*)d_in[2];
    const float* Wsf[3] = {(const float*)d_in[3], (const float*)d_in[7], (const float*)d_in[11]};
    const float* bsv[3] = {(const float*)d_in[4], (const float*)d_in[8], (const float*)d_in[12]};
    const float* Wnf[3] = {(const float*)d_in[5], (const float*)d_in[9], (const float*)d_in[13]};
    const float* bnv[3] = {(const float*)d_in[6], (const float*)d_in[10], (const float*)d_in[14]};
    const float* Wo = (const float*)d_in[15];
    const float* bo = (const float*)d_in[16];
    float* out = (float*)d_out;

    char* ws = (char*)d_ws;
    const size_t HB = (size_t)N_NODES * F * 2;  // 25.6 MB bf16
    ushort* h0 = (ushort*)ws;
    ushort* hA = (ushort*)(ws + HB);
    ushort* hB = (ushort*)(ws + 2 * HB);
    ushort* agg = (ushort*)(ws + 3 * HB);
    char* p = ws + 4 * HB;
    ushort* wt = (ushort*)p;       p += 6 * 16384 * 2;          // 6x [128][128] bf16
    ushort* wto = (ushort*)p;      p += 64 * 128 * 2;           // [64][128] bf16
    p = (char*)(((size_t)p + 255) & ~(size_t)255);
    int* deg = (int*)p;            p += (size_t)N_NODES * 4;
    float* inv = (float*)p;        p += (size_t)N_NODES * 4;
    int* rp = (int*)p;             p += (size_t)(N_NODES + 1) * 4 + 252;
    int* cnt = (int*)p;            p += (size_t)N_NODES * 4;
    int* col = (int*)p;            p += (size_t)N_EDGES * 4;
    int* blksum = (int*)p;

    const int nScanBlk = (N_NODES + 1023) / 1024;  // 98
    const int edgeBlk = (N_EDGES + 255) / 256;
    const int nodeBlk = (N_NODES + 255) / 256;

    // prep: convert features + weights; build CSR
    k_cvt<<<(N_NODES * F / 4 + 255) / 256, 256, 0, stream>>>((const float4*)feat, h0);
    k_wt<<<dim3(128, 6), 128, 0, stream>>>(Wsf[0], Wnf[0], Wsf[1], Wnf[1], Wsf[2], Wnf[2], wt);
    k_wto<<<64, 128, 0, stream>>>(Wo, wto);
    k_zero<<<nodeBlk, 256, 0, stream>>>(deg, cnt);
    k_hist<<<edgeBlk, 256, 0, stream>>>(dst, deg);
    k_scan1<<<nScanBlk, 256, 0, stream>>>(deg, rp, blksum);
    k_scan2<<<1, 128, 0, stream>>>(blksum, nScanBlk);
    k_scan3<<<nodeBlk, 256, 0, stream>>>(deg, rp, blksum, inv);
    k_fill<<<edgeBlk, 256, 0, stream>>>(src, dst, rp, cnt, col);

    const int aggBlk = (N_NODES * 64 + 255) / 256;   // 25000
    const int gemmBlk = (N_NODES + 127) / 128;       // 782

    ushort* Wt0s = wt + 0 * 16384; ushort* Wt0n = wt + 1 * 16384;
    ushort* Wt1s = wt + 2 * 16384; ushort* Wt1n = wt + 3 * 16384;
    ushort* Wt2s = wt + 4 * 16384; ushort* Wt2n = wt + 5 * 16384;

    // layer 0
    k_agg<<<aggBlk, 256, 0, stream>>>(h0, rp, col, inv, agg);
    k_gemm<1><<<gemmBlk, 256, 0, stream>>>(h0, agg, Wt0s, Wt0n, bsv[0], bnv[0], hA);
    // layer 1
    k_agg<<<aggBlk, 256, 0, stream>>>(hA, rp, col, inv, agg);
    k_gemm<1><<<gemmBlk, 256, 0, stream>>>(hA, agg, Wt1s, Wt1n, bsv[1], bnv[1], hB);
    // layer 2
    k_agg<<<aggBlk, 256, 0, stream>>>(hB, rp, col, inv, agg);
    k_gemm<0><<<gemmBlk, 256, 0, stream>>>(hB, agg, Wt2s, Wt2n, bsv[2], bnv[2], hA);
    // final linear
    k_final<<<gemmBlk, 256, 0, stream>>>(hA, wto, bo, out);
}

// Round 5
// 284.638 us; speedup vs baseline: 2.3133x; 1.2771x over previous
//
#include <hip/hip_runtime.h>

#define N_NODES 100000
#define N_EDGES 600000
#define F 128
#define OUTD 64

typedef short bf16x8 __attribute__((ext_vector_type(8)));
typedef float f32x4 __attribute__((ext_vector_type(4)));

__device__ __forceinline__ unsigned short f2bf(float f) {
    union { float f; unsigned u; } v; v.f = f;
    unsigned u = v.u;
    return (unsigned short)((u + 0x7FFFu + ((u >> 16) & 1u)) >> 16);
}
__device__ __forceinline__ float bf2f(unsigned short s) {
    union { unsigned u; float f; } v; v.u = ((unsigned)s) << 16;
    return v.f;
}

__device__ __forceinline__ void async_copy16(void* lds, const void* g) {
    __builtin_amdgcn_global_load_lds((const __attribute__((address_space(1))) void*)g,
                                     (__attribute__((address_space(3))) void*)lds, 16, 0, 0);
}

// ---------------- feature convert fp32 -> bf16 ----------------
__global__ __launch_bounds__(256) void k_cvt(const float4* __restrict__ in, ushort* __restrict__ out) {
    int i = blockIdx.x * blockDim.x + threadIdx.x;  // 3.2M float4
    float4 v = in[i];
    ushort4 o;
    o.x = f2bf(v.x); o.y = f2bf(v.y); o.z = f2bf(v.z); o.w = f2bf(v.w);
    *(ushort4*)&out[i * 4] = o;
}

// ---------------- weight transpose+convert: Wt[n][k] = bf16(W[k][n]) ----------------
__global__ __launch_bounds__(128) void k_wt(const float* __restrict__ w0, const float* __restrict__ w1,
                                            const float* __restrict__ w2, const float* __restrict__ w3,
                                            const float* __restrict__ w4, const float* __restrict__ w5,
                                            ushort* __restrict__ wt) {
    int which = blockIdx.y;
    const float* s = w0;
    if (which == 1) s = w1; else if (which == 2) s = w2; else if (which == 3) s = w3;
    else if (which == 4) s = w4; else if (which == 5) s = w5;
    int n = blockIdx.x, k = threadIdx.x;
    wt[which * 16384 + n * 128 + k] = f2bf(s[k * 128 + n]);
}

__global__ __launch_bounds__(128) void k_wto(const float* __restrict__ w, ushort* __restrict__ wt) {
    int n = blockIdx.x, k = threadIdx.x;
    wt[n * 128 + k] = f2bf(w[k * 64 + n]);
}

// ---------------- CSR build ----------------
__global__ __launch_bounds__(256) void k_zero(int* __restrict__ a, int* __restrict__ b) {
    int i = blockIdx.x * blockDim.x + threadIdx.x;
    if (i < N_NODES) { a[i] = 0; b[i] = 0; }
}

__global__ __launch_bounds__(256) void k_hist(const int* __restrict__ dst, int* __restrict__ deg) {
    int e = blockIdx.x * blockDim.x + threadIdx.x;
    if (e < N_EDGES) atomicAdd(&deg[dst[e]], 1);
}

__global__ __launch_bounds__(256) void k_scan1(const int* __restrict__ deg, int* __restrict__ row_ptr,
                                               int* __restrict__ blksum) {
    __shared__ int sm[256];
    int t = threadIdx.x, b = blockIdx.x;
    int base = b * 1024 + t * 4;
    int v[4];
    int run = 0;
#pragma unroll
    for (int i = 0; i < 4; i++) {
        int idx = base + i;
        int d = (idx < N_NODES) ? deg[idx] : 0;
        run += d;
        v[i] = run;
    }
    sm[t] = run;
    __syncthreads();
    for (int off = 1; off < 256; off <<= 1) {
        int add = 0;
        if (t >= off) add = sm[t - off];
        __syncthreads();
        sm[t] += add;
        __syncthreads();
    }
    int excl = sm[t] - run;
#pragma unroll
    for (int i = 0; i < 4; i++) {
        int idx = base + i;
        if (idx < N_NODES) row_ptr[idx + 1] = excl + v[i];
    }
    if (t == 255) blksum[b] = sm[255];
}

__global__ __launch_bounds__(128) void k_scan2(int* __restrict__ blksum, int nblk) {
    __shared__ int sm[128];
    int t = threadIdx.x;
    int v = (t < nblk) ? blksum[t] : 0;
    sm[t] = v;
    __syncthreads();
    for (int off = 1; off < 128; off <<= 1) {
        int add = 0;
        if (t >= off) add = sm[t - off];
        __syncthreads();
        sm[t] += add;
        __syncthreads();
    }
    if (t < nblk) blksum[t] = sm[t] - v;  // exclusive
}

__global__ __launch_bounds__(256) void k_scan3(const int* __restrict__ deg, int* __restrict__ row_ptr,
                                               const int* __restrict__ blksum, float* __restrict__ inv_deg) {
    int i = blockIdx.x * blockDim.x + threadIdx.x;
    if (i == 0) row_ptr[0] = 0;
    if (i < N_NODES) {
        row_ptr[i + 1] += blksum[i >> 10];
        int d = deg[i];
        inv_deg[i] = 1.0f / (float)(d > 0 ? d : 1);
    }
}

__global__ __launch_bounds__(256) void k_fill(const int* __restrict__ src, const int* __restrict__ dst,
                                              const int* __restrict__ row_ptr, int* __restrict__ cnt,
                                              int* __restrict__ col) {
    int e = blockIdx.x * blockDim.x + threadIdx.x;
    if (e < N_EDGES) {
        int d = dst[e];
        int p = row_ptr[d] + atomicAdd(&cnt[d], 1);
        col[p] = src[e];
    }
}

// ---------------- aggregation (bf16 h): one wave per node, 4x unrolled for MLP ----------------
__global__ __launch_bounds__(256) void k_agg(const ushort* __restrict__ h, const int* __restrict__ row_ptr,
                                             const int* __restrict__ col, const float* __restrict__ inv_deg,
                                             ushort* __restrict__ out) {
    int gtid = blockIdx.x * blockDim.x + threadIdx.x;
    int node = gtid >> 6;
    int lane = threadIdx.x & 63;
    if (node >= N_NODES) return;
    int s = row_ptr[node], e = row_ptr[node + 1];
    const unsigned* hp = (const unsigned*)h;
    float ax0 = 0.f, ay0 = 0.f, ax1 = 0.f, ay1 = 0.f;
    int p = s;
    for (; p + 4 <= e; p += 4) {
        int c0 = col[p + 0], c1 = col[p + 1], c2 = col[p + 2], c3 = col[p + 3];
        unsigned v0 = hp[(size_t)c0 * 64 + lane];
        unsigned v1 = hp[(size_t)c1 * 64 + lane];
        unsigned v2 = hp[(size_t)c2 * 64 + lane];
        unsigned v3 = hp[(size_t)c3 * 64 + lane];
        ax0 += bf2f((unsigned short)(v0 & 0xFFFFu)); ay0 += bf2f((unsigned short)(v0 >> 16));
        ax1 += bf2f((unsigned short)(v1 & 0xFFFFu)); ay1 += bf2f((unsigned short)(v1 >> 16));
        ax0 += bf2f((unsigned short)(v2 & 0xFFFFu)); ay0 += bf2f((unsigned short)(v2 >> 16));
        ax1 += bf2f((unsigned short)(v3 & 0xFFFFu)); ay1 += bf2f((unsigned short)(v3 >> 16));
    }
    for (; p < e; ++p) {
        int c = col[p];
        unsigned v = hp[(size_t)c * 64 + lane];
        ax0 += bf2f((unsigned short)(v & 0xFFFFu)); ay0 += bf2f((unsigned short)(v >> 16));
    }
    float iv = inv_deg[node];
    float ax = (ax0 + ax1) * iv, ay = (ay0 + ay1) * iv;
    unsigned o = (unsigned)f2bf(ax) | ((unsigned)f2bf(ay) << 16);
    ((unsigned*)out)[(size_t)node * 64 + lane] = o;
}

// ---------------- MFMA fused dual GEMM (round-2 known-good structure) ----------------
// BM=128, BN=128, K=256 (h||hn), BK=32. 4 waves in 2x2, each 64x64 (4x4 frags of 16x16x32).
template <int RELU>
__global__ __launch_bounds__(256) void k_gemm(const ushort* __restrict__ h, const ushort* __restrict__ hn,
                                              const ushort* __restrict__ Wts, const ushort* __restrict__ Wtn,
                                              const float* __restrict__ bs, const float* __restrict__ bn,
                                              ushort* __restrict__ out) {
    __shared__ ushort smem[16384];  // 32KB: staging As[128][32] + Bs[128][32]; epilogue cbuf
    ushort* As = smem;          // 4096 shorts
    ushort* Bs = smem + 4096;   // 4096 shorts
    const int t = threadIdx.x;
    const int w = t >> 6, l = t & 63;
    const int wr = w >> 1, wc = w & 1;
    const int m0 = blockIdx.x * 128;

    f32x4 acc[4][4];
#pragma unroll
    for (int m = 0; m < 4; m++)
#pragma unroll
        for (int n = 0; n < 4; n++) acc[m][n] = (f32x4){0.f, 0.f, 0.f, 0.f};

    const int arow = t >> 2;          // 0..63
    const int acolsh = (t & 3) * 8;   // short offset within 32-k row

    for (int kt = 0; kt < 8; ++kt) {
        const ushort* Asrc = (kt < 4) ? h : hn;
        const ushort* Bsrc = (kt < 4) ? Wts : Wtn;
        const int koff = (kt & 3) * 32;
#pragma unroll
        for (int i = 0; i < 2; ++i) {
            int row = m0 + i * 64 + arow;
            if (row > N_NODES - 1) row = N_NODES - 1;
            async_copy16(As + i * 2048 + w * 512, Asrc + (size_t)row * 128 + koff + acolsh);
            async_copy16(Bs + i * 2048 + w * 512, Bsrc + (size_t)(i * 64 + arow) * 128 + koff + acolsh);
        }
        __syncthreads();
        const int kcol = (l >> 4) * 8;
        bf16x8 aF[4], bF[4];
#pragma unroll
        for (int m = 0; m < 4; m++) aF[m] = *(const bf16x8*)&As[(wr * 64 + m * 16 + (l & 15)) * 32 + kcol];
#pragma unroll
        for (int n = 0; n < 4; n++) bF[n] = *(const bf16x8*)&Bs[(wc * 64 + n * 16 + (l & 15)) * 32 + kcol];
#pragma unroll
        for (int m = 0; m < 4; m++)
#pragma unroll
            for (int n = 0; n < 4; n++)
                acc[m][n] = __builtin_amdgcn_mfma_f32_16x16x32_bf16(aF[m], bF[n], acc[m][n], 0, 0, 0);
        __syncthreads();
    }

    // epilogue: bias+act, stage through per-wave LDS tile for coalesced bf16 stores
    float bias[4];
#pragma unroll
    for (int n = 0; n < 4; n++) {
        int gc = wc * 64 + n * 16 + (l & 15);
        bias[n] = bs[gc] + bn[gc];
    }
    ushort* cw = smem + w * 4096;  // [64][64] bf16 per wave
#pragma unroll
    for (int m = 0; m < 4; m++)
#pragma unroll
        for (int n = 0; n < 4; n++) {
            int lr0 = m * 16 + (l >> 4) * 4;
            int lc = n * 16 + (l & 15);
#pragma unroll
            for (int j = 0; j < 4; j++) {
                float v = acc[m][n][j] + bias[n];
                if (RELU) v = fmaxf(v, 0.f);
                cw[(lr0 + j) * 64 + lc] = f2bf(v);
            }
        }
    // same-wave read-back (no barrier needed), coalesced 16B stores
#pragma unroll
    for (int r = 0; r < 8; r++) {
        int row = r * 8 + (l >> 3);
        int cs = (l & 7) * 8;
        bf16x8 vv = *(const bf16x8*)&cw[row * 64 + cs];
        int grow = m0 + wr * 64 + row;
        if (grow < N_NODES) *(bf16x8*)&out[(size_t)grow * 128 + wc * 64 + cs] = vv;
    }
}

// ---------------- final linear MFMA: out(fp32) = h @ W_out + b_out ----------------
// BM=128, BN=64, K=128, BK=32. 4 waves 2x2, each 64x32 (4x2 frags).
__global__ __launch_bounds__(256) void k_final(const ushort* __restrict__ h, const ushort* __restrict__ Wto,
                                               const float* __restrict__ bo, float* __restrict__ out) {
    __shared__ ushort smem[16384];
    ushort* As = smem;         // [128][32]
    ushort* Bs = smem + 4096;  // [64][32]
    const int t = threadIdx.x;
    const int w = t >> 6, l = t & 63;
    const int wr = w >> 1, wc = w & 1;
    const int m0 = blockIdx.x * 128;

    f32x4 acc[4][2];
#pragma unroll
    for (int m = 0; m < 4; m++)
#pragma unroll
        for (int n = 0; n < 2; n++) acc[m][n] = (f32x4){0.f, 0.f, 0.f, 0.f};

    const int arow = t >> 2;
    const int acolsh = (t & 3) * 8;

    for (int kt = 0; kt < 4; ++kt) {
        const int koff = kt * 32;
#pragma unroll
        for (int i = 0; i < 2; ++i) {
            int row = m0 + i * 64 + arow;
            if (row > N_NODES - 1) row = N_NODES - 1;
            async_copy16(As + i * 2048 + w * 512, h + (size_t)row * 128 + koff + acolsh);
        }
        async_copy16(Bs + w * 512, Wto + (size_t)arow * 128 + koff + acolsh);
        __syncthreads();
        const int kcol = (l >> 4) * 8;
        bf16x8 aF[4], bF[2];
#pragma unroll
        for (int m = 0; m < 4; m++) aF[m] = *(const bf16x8*)&As[(wr * 64 + m * 16 + (l & 15)) * 32 + kcol];
#pragma unroll
        for (int n = 0; n < 2; n++) bF[n] = *(const bf16x8*)&Bs[(wc * 32 + n * 16 + (l & 15)) * 32 + kcol];
#pragma unroll
        for (int m = 0; m < 4; m++)
#pragma unroll
            for (int n = 0; n < 2; n++)
                acc[m][n] = __builtin_amdgcn_mfma_f32_16x16x32_bf16(aF[m], bF[n], acc[m][n], 0, 0, 0);
        __syncthreads();
    }

    float bias[2];
#pragma unroll
    for (int n = 0; n < 2; n++) bias[n] = bo[wc * 32 + n * 16 + (l & 15)];

    float* cw = (float*)smem + w * 2048;  // [64][32] fp32 per wave
#pragma unroll
    for (int m = 0; m < 4; m++)
#pragma unroll
        for (int n = 0; n < 2; n++) {
            int lr0 = m * 16 + (l >> 4) * 4;
            int lc = n * 16 + (l & 15);
#pragma unroll
            for (int j = 0; j < 4; j++) cw[(lr0 + j) * 32 + lc] = acc[m][n][j] + bias[n];
        }
#pragma unroll
    for (int r = 0; r < 8; r++) {
        int row = r * 8 + (l >> 3);
        int cf = (l & 7) * 4;
        float4 vv = *(const float4*)&cw[row * 32 + cf];
        int grow = m0 + wr * 64 + row;
        if (grow < N_NODES) *(float4*)&out[(size_t)grow * 64 + wc * 32 + cf] = vv;
    }
}

extern "C" void kernel_launch(void* const* d_in, const int* in_sizes, int n_in,
                              void* d_out, int out_size, void* d_ws, size_t ws_size,
                              hipStream_t stream) {
    const float* feat = (const float*)d_in[0];
    const int* src = (const int*)d_in[1];
    const int* dst = (const int*)d_in[2];
    const float* Wsf[3] = {(const float*)d_in[3], (const float*)d_in[7], (const float*)d_in[11]};
    const float* bsv[3] = {(const float*)d_in[4], (const float*)d_in[8], (const float*)d_in[12]};
    const float* Wnf[3] = {(const float*)d_in[5], (const float*)d_in[9], (const float*)d_in[13]};
    const float* bnv[3] = {(const float*)d_in[6], (const float*)d_in[10], (const float*)d_in[14]};
    const float* Wo = (const float*)d_in[15];
    const float* bo = (const float*)d_in[16];
    float* out = (float*)d_out;

    char* ws = (char*)d_ws;
    const size_t HB = (size_t)N_NODES * F * 2;  // 25.6 MB bf16
    ushort* h0 = (ushort*)ws;
    ushort* hA = (ushort*)(ws + HB);
    ushort* hB = (ushort*)(ws + 2 * HB);
    ushort* agg = (ushort*)(ws + 3 * HB);
    char* p = ws + 4 * HB;
    ushort* wt = (ushort*)p;       p += 6 * 16384 * 2;          // 6x [128][128] bf16
    ushort* wto = (ushort*)p;      p += 64 * 128 * 2;           // [64][128] bf16
    p = (char*)(((size_t)p + 255) & ~(size_t)255);
    int* deg = (int*)p;            p += (size_t)N_NODES * 4;
    float* inv = (float*)p;        p += (size_t)N_NODES * 4;
    int* rp = (int*)p;             p += (size_t)(N_NODES + 1) * 4 + 252;
    int* cnt = (int*)p;            p += (size_t)N_NODES * 4;
    int* col = (int*)p;            p += (size_t)N_EDGES * 4;
    int* blksum = (int*)p;

    const int nScanBlk = (N_NODES + 1023) / 1024;  // 98
    const int edgeBlk = (N_EDGES + 255) / 256;
    const int nodeBlk = (N_NODES + 255) / 256;

    // prep: convert features + weights; build CSR
    k_cvt<<<(N_NODES * F / 4 + 255) / 256, 256, 0, stream>>>((const float4*)feat, h0);
    k_wt<<<dim3(128, 6), 128, 0, stream>>>(Wsf[0], Wnf[0], Wsf[1], Wnf[1], Wsf[2], Wnf[2], wt);
    k_wto<<<64, 128, 0, stream>>>(Wo, wto);
    k_zero<<<nodeBlk, 256, 0, stream>>>(deg, cnt);
    k_hist<<<edgeBlk, 256, 0, stream>>>(dst, deg);
    k_scan1<<<nScanBlk, 256, 0, stream>>>(deg, rp, blksum);
    k_scan2<<<1, 128, 0, stream>>>(blksum, nScanBlk);
    k_scan3<<<nodeBlk, 256, 0, stream>>>(deg, rp, blksum, inv);
    k_fill<<<edgeBlk, 256, 0, stream>>>(src, dst, rp, cnt, col);

    const int aggBlk = (N_NODES * 64 + 255) / 256;   // 25000
    const int gemmBlk = (N_NODES + 127) / 128;       // 782

    ushort* Wt0s = wt + 0 * 16384; ushort* Wt0n = wt + 1 * 16384;
    ushort* Wt1s = wt + 2 * 16384; ushort* Wt1n = wt + 3 * 16384;
    ushort* Wt2s = wt + 4 * 16384; ushort* Wt2n = wt + 5 * 16384;

    // layer 0
    k_agg<<<aggBlk, 256, 0, stream>>>(h0, rp, col, inv, agg);
    k_gemm<1><<<gemmBlk, 256, 0, stream>>>(h0, agg, Wt0s, Wt0n, bsv[0], bnv[0], hA);
    // layer 1
    k_agg<<<aggBlk, 256, 0, stream>>>(hA, rp, col, inv, agg);
    k_gemm<1><<<gemmBlk, 256, 0, stream>>>(hA, agg, Wt1s, Wt1n, bsv[1], bnv[1], hB);
    // layer 2
    k_agg<<<aggBlk, 256, 0, stream>>>(hB, rp, col, inv, agg);
    k_gemm<0><<<gemmBlk, 256, 0, stream>>>(hB, agg, Wt2s, Wt2n, bsv[2], bnv[2], hA);
    // final linear
    k_final<<<gemmBlk, 256, 0, stream>>>(hA, wto, bo, out);
}

// Round 6
// 246.215 us; speedup vs baseline: 2.6743x; 1.1561x over previous
//
#include <hip/hip_runtime.h>

#define N_NODES 100000
#define N_EDGES 600000
#define F 128
#define OUTD 64

typedef short bf16x8 __attribute__((ext_vector_type(8)));
typedef float f32x4 __attribute__((ext_vector_type(4)));

__device__ __forceinline__ unsigned short f2bf(float f) {
    union { float f; unsigned u; } v; v.f = f;
    unsigned u = v.u;
    return (unsigned short)((u + 0x7FFFu + ((u >> 16) & 1u)) >> 16);
}
__device__ __forceinline__ float bf2f(unsigned short s) {
    union { unsigned u; float f; } v; v.u = ((unsigned)s) << 16;
    return v.f;
}

__device__ __forceinline__ void async_copy16(void* lds, const void* g) {
    __builtin_amdgcn_global_load_lds((const __attribute__((address_space(1))) void*)g,
                                     (__attribute__((address_space(3))) void*)lds, 16, 0, 0);
}

// ---------------- feature convert fp32 -> bf16 ----------------
__global__ __launch_bounds__(256) void k_cvt(const float4* __restrict__ in, ushort* __restrict__ out) {
    int i = blockIdx.x * blockDim.x + threadIdx.x;  // 3.2M float4
    float4 v = in[i];
    ushort4 o;
    o.x = f2bf(v.x); o.y = f2bf(v.y); o.z = f2bf(v.z); o.w = f2bf(v.w);
    *(ushort4*)&out[i * 4] = o;
}

// ---------------- weight transpose+convert: Wt[n][k] = bf16(W[k][n]) ----------------
__global__ __launch_bounds__(128) void k_wt(const float* __restrict__ w0, const float* __restrict__ w1,
                                            const float* __restrict__ w2, const float* __restrict__ w3,
                                            const float* __restrict__ w4, const float* __restrict__ w5,
                                            ushort* __restrict__ wt) {
    int which = blockIdx.y;
    const float* s = w0;
    if (which == 1) s = w1; else if (which == 2) s = w2; else if (which == 3) s = w3;
    else if (which == 4) s = w4; else if (which == 5) s = w5;
    int n = blockIdx.x, k = threadIdx.x;
    wt[which * 16384 + n * 128 + k] = f2bf(s[k * 128 + n]);
}

__global__ __launch_bounds__(128) void k_wto(const float* __restrict__ w, ushort* __restrict__ wt) {
    int n = blockIdx.x, k = threadIdx.x;
    wt[n * 128 + k] = f2bf(w[k * 64 + n]);
}

// ---------------- CSR build ----------------
__global__ __launch_bounds__(256) void k_zero(int* __restrict__ a, int* __restrict__ b) {
    int i = blockIdx.x * blockDim.x + threadIdx.x;
    if (i < N_NODES) { a[i] = 0; b[i] = 0; }
}

__global__ __launch_bounds__(256) void k_hist(const int* __restrict__ dst, int* __restrict__ deg) {
    int e = blockIdx.x * blockDim.x + threadIdx.x;
    if (e < N_EDGES) atomicAdd(&deg[dst[e]], 1);
}

__global__ __launch_bounds__(256) void k_scan1(const int* __restrict__ deg, int* __restrict__ row_ptr,
                                               int* __restrict__ blksum) {
    __shared__ int sm[256];
    int t = threadIdx.x, b = blockIdx.x;
    int base = b * 1024 + t * 4;
    int v[4];
    int run = 0;
#pragma unroll
    for (int i = 0; i < 4; i++) {
        int idx = base + i;
        int d = (idx < N_NODES) ? deg[idx] : 0;
        run += d;
        v[i] = run;
    }
    sm[t] = run;
    __syncthreads();
    for (int off = 1; off < 256; off <<= 1) {
        int add = 0;
        if (t >= off) add = sm[t - off];
        __syncthreads();
        sm[t] += add;
        __syncthreads();
    }
    int excl = sm[t] - run;
#pragma unroll
    for (int i = 0; i < 4; i++) {
        int idx = base + i;
        if (idx < N_NODES) row_ptr[idx + 1] = excl + v[i];
    }
    if (t == 255) blksum[b] = sm[255];
}

__global__ __launch_bounds__(128) void k_scan2(int* __restrict__ blksum, int nblk) {
    __shared__ int sm[128];
    int t = threadIdx.x;
    int v = (t < nblk) ? blksum[t] : 0;
    sm[t] = v;
    __syncthreads();
    for (int off = 1; off < 128; off <<= 1) {
        int add = 0;
        if (t >= off) add = sm[t - off];
        __syncthreads();
        sm[t] += add;
        __syncthreads();
    }
    if (t < nblk) blksum[t] = sm[t] - v;  // exclusive
}

__global__ __launch_bounds__(256) void k_scan3(const int* __restrict__ deg, int* __restrict__ row_ptr,
                                               const int* __restrict__ blksum, float* __restrict__ inv_deg) {
    int i = blockIdx.x * blockDim.x + threadIdx.x;
    if (i == 0) row_ptr[0] = 0;
    if (i < N_NODES) {
        row_ptr[i + 1] += blksum[i >> 10];
        int d = deg[i];
        inv_deg[i] = 1.0f / (float)(d > 0 ? d : 1);
    }
}

__global__ __launch_bounds__(256) void k_fill(const int* __restrict__ src, const int* __restrict__ dst,
                                              const int* __restrict__ row_ptr, int* __restrict__ cnt,
                                              int* __restrict__ col) {
    int e = blockIdx.x * blockDim.x + threadIdx.x;
    if (e < N_EDGES) {
        int d = dst[e];
        int p = row_ptr[d] + atomicAdd(&cnt[d], 1);
        col[p] = src[e];
    }
}

// ---------------- aggregation: half-wave (32 lanes) per node, uint2 loads, 4x unroll ----------------
__device__ __forceinline__ void acc4(uint2 v, float& a, float& b, float& c, float& d) {
    a += bf2f((unsigned short)(v.x & 0xFFFFu));
    b += bf2f((unsigned short)(v.x >> 16));
    c += bf2f((unsigned short)(v.y & 0xFFFFu));
    d += bf2f((unsigned short)(v.y >> 16));
}

__global__ __launch_bounds__(256) void k_agg(const ushort* __restrict__ h, const int* __restrict__ row_ptr,
                                             const int* __restrict__ col, const float* __restrict__ inv_deg,
                                             ushort* __restrict__ out) {
    int gtid = blockIdx.x * blockDim.x + threadIdx.x;
    int node = gtid >> 5;            // one node per 32-lane half-wave
    int lane = threadIdx.x & 31;     // 4 bf16 per lane (8B)
    if (node >= N_NODES) return;
    int s = row_ptr[node], e = row_ptr[node + 1];
    const uint2* hp = (const uint2*)h;  // row stride = 32 uint2
    float ax0 = 0.f, ay0 = 0.f, az0 = 0.f, aw0 = 0.f;
    float ax1 = 0.f, ay1 = 0.f, az1 = 0.f, aw1 = 0.f;
    int p = s;
    for (; p + 4 <= e; p += 4) {
        int c0 = col[p + 0], c1 = col[p + 1], c2 = col[p + 2], c3 = col[p + 3];
        uint2 v0 = hp[(size_t)c0 * 32 + lane];
        uint2 v1 = hp[(size_t)c1 * 32 + lane];
        uint2 v2 = hp[(size_t)c2 * 32 + lane];
        uint2 v3 = hp[(size_t)c3 * 32 + lane];
        acc4(v0, ax0, ay0, az0, aw0);
        acc4(v1, ax1, ay1, az1, aw1);
        acc4(v2, ax0, ay0, az0, aw0);
        acc4(v3, ax1, ay1, az1, aw1);
    }
    for (; p < e; ++p) {
        int c = col[p];
        uint2 v = hp[(size_t)c * 32 + lane];
        acc4(v, ax0, ay0, az0, aw0);
    }
    float iv = inv_deg[node];
    float fx = (ax0 + ax1) * iv, fy = (ay0 + ay1) * iv;
    float fz = (az0 + az1) * iv, fw = (aw0 + aw1) * iv;
    uint2 o;
    o.x = (unsigned)f2bf(fx) | ((unsigned)f2bf(fy) << 16);
    o.y = (unsigned)f2bf(fz) | ((unsigned)f2bf(fw) << 16);
    ((uint2*)out)[(size_t)node * 32 + lane] = o;
}

// ---------------- MFMA fused dual GEMM, double-buffered with counted vmcnt ----------------
// BM=128, BN=128, K=256 (h||hn), BK=32. 4 waves 2x2, each 64x64 (4x4 frags of 16x16x32).
// Fence discipline (r3/r4 post-mortem): top barrier = counted vmcnt (prefetch in flight),
// end barrier MUST drain lgkmcnt(0) so no wave's ds_reads are in flight when the next
// iteration's global_load_lds DMA overwrites this buffer.
template <int RELU>
__global__ __launch_bounds__(256) void k_gemm(const ushort* __restrict__ h, const ushort* __restrict__ hn,
                                              const ushort* __restrict__ Wts, const ushort* __restrict__ Wtn,
                                              const float* __restrict__ bs, const float* __restrict__ bn,
                                              ushort* __restrict__ out) {
    __shared__ ushort smem[16384];  // 2 x (As[128][32] + Bs[128][32]); epilogue reuses
    const int t = threadIdx.x;
    const int w = t >> 6, l = t & 63;
    const int wr = w >> 1, wc = w & 1;
    const int m0 = blockIdx.x * 128;

    f32x4 acc[4][4];
#pragma unroll
    for (int m = 0; m < 4; m++)
#pragma unroll
        for (int n = 0; n < 4; n++) acc[m][n] = (f32x4){0.f, 0.f, 0.f, 0.f};

    float bias[4];
#pragma unroll
    for (int n = 0; n < 4; n++) {
        int gc = wc * 64 + n * 16 + (l & 15);
        bias[n] = bs[gc] + bn[gc];
    }

    const int arow = t >> 2;          // 0..63
    const int acolsh = (t & 3) * 8;   // short offset within 32-k row

#define STAGE(BUF, KT)                                                                            \
    do {                                                                                          \
        ushort* As_ = smem + (BUF) * 8192;                                                        \
        ushort* Bs_ = As_ + 4096;                                                                 \
        const ushort* Asrc = ((KT) < 4) ? h : hn;                                                 \
        const ushort* Bsrc = ((KT) < 4) ? Wts : Wtn;                                              \
        const int koff = ((KT) & 3) * 32;                                                         \
        _Pragma("unroll") for (int i = 0; i < 2; ++i) {                                           \
            int row = m0 + i * 64 + arow;                                                         \
            if (row > N_NODES - 1) row = N_NODES - 1;                                             \
            async_copy16(As_ + i * 2048 + w * 512, Asrc + (size_t)row * 128 + koff + acolsh);     \
            async_copy16(Bs_ + i * 2048 + w * 512,                                                \
                         Bsrc + (size_t)(i * 64 + arow) * 128 + koff + acolsh);                   \
        }                                                                                         \
    } while (0)

    STAGE(0, 0);
    for (int kt = 0; kt < 8; ++kt) {
        const int cur = kt & 1;
        if (kt < 7) {
            STAGE(cur ^ 1, kt + 1);
            // tile kt's 4 loads are the oldest outstanding -> vmcnt(4) completes them;
            // the 4 prefetch loads stay in flight across the barrier.
            asm volatile("s_waitcnt vmcnt(4)\n\ts_barrier" ::: "memory");
        } else {
            asm volatile("s_waitcnt vmcnt(0)\n\ts_barrier" ::: "memory");
        }
        const ushort* As = smem + cur * 8192;
        const ushort* Bs = As + 4096;
        const int kcol = (l >> 4) * 8;
        bf16x8 aF[4], bF[4];
#pragma unroll
        for (int m = 0; m < 4; m++) aF[m] = *(const bf16x8*)&As[(wr * 64 + m * 16 + (l & 15)) * 32 + kcol];
#pragma unroll
        for (int n = 0; n < 4; n++) bF[n] = *(const bf16x8*)&Bs[(wc * 64 + n * 16 + (l & 15)) * 32 + kcol];
#pragma unroll
        for (int m = 0; m < 4; m++)
#pragma unroll
            for (int n = 0; n < 4; n++)
                acc[m][n] = __builtin_amdgcn_mfma_f32_16x16x32_bf16(aF[m], bF[n], acc[m][n], 0, 0, 0);
        // drain this wave's ds_reads BEFORE the barrier so next iter's DMA can't
        // overwrite LDS words with reads still in flight (the r3/r4 race).
        asm volatile("s_waitcnt lgkmcnt(0)\n\ts_barrier" ::: "memory");
    }
#undef STAGE
    __syncthreads();  // full drain; repurpose smem for epilogue

    ushort* cw = smem + w * 4096;  // [64][64] bf16 per wave
#pragma unroll
    for (int m = 0; m < 4; m++)
#pragma unroll
        for (int n = 0; n < 4; n++) {
            int lr0 = m * 16 + (l >> 4) * 4;
            int lc = n * 16 + (l & 15);
#pragma unroll
            for (int j = 0; j < 4; j++) {
                float v = acc[m][n][j] + bias[n];
                if (RELU) v = fmaxf(v, 0.f);
                cw[(lr0 + j) * 64 + lc] = f2bf(v);
            }
        }
    // same-wave read-back (no barrier needed), coalesced 16B stores
#pragma unroll
    for (int r = 0; r < 8; r++) {
        int row = r * 8 + (l >> 3);
        int cs = (l & 7) * 8;
        bf16x8 vv = *(const bf16x8*)&cw[row * 64 + cs];
        int grow = m0 + wr * 64 + row;
        if (grow < N_NODES) *(bf16x8*)&out[(size_t)grow * 128 + wc * 64 + cs] = vv;
    }
}

// ---------------- final linear MFMA, double-buffered: out(fp32) = h @ W_out + b_out ----------------
// BM=128, BN=64, K=128, BK=32. 4 waves 2x2, each 64x32 (4x2 frags).
__global__ __launch_bounds__(256) void k_final(const ushort* __restrict__ h, const ushort* __restrict__ Wto,
                                               const float* __restrict__ bo, float* __restrict__ out) {
    __shared__ ushort smem[16384];
    const int t = threadIdx.x;
    const int w = t >> 6, l = t & 63;
    const int wr = w >> 1, wc = w & 1;
    const int m0 = blockIdx.x * 128;

    f32x4 acc[4][2];
#pragma unroll
    for (int m = 0; m < 4; m++)
#pragma unroll
        for (int n = 0; n < 2; n++) acc[m][n] = (f32x4){0.f, 0.f, 0.f, 0.f};

    float bias[2];
#pragma unroll
    for (int n = 0; n < 2; n++) bias[n] = bo[wc * 32 + n * 16 + (l & 15)];

    const int arow = t >> 2;
    const int acolsh = (t & 3) * 8;

#define STAGEF(BUF, KT)                                                                          \
    do {                                                                                         \
        ushort* As_ = smem + (BUF) * 8192;                                                       \
        ushort* Bs_ = As_ + 4096;                                                                \
        const int koff = (KT) * 32;                                                              \
        _Pragma("unroll") for (int i = 0; i < 2; ++i) {                                          \
            int row = m0 + i * 64 + arow;                                                        \
            if (row > N_NODES - 1) row = N_NODES - 1;                                            \
            async_copy16(As_ + i * 2048 + w * 512, h + (size_t)row * 128 + koff + acolsh);       \
        }                                                                                        \
        async_copy16(Bs_ + w * 512, Wto + (size_t)arow * 128 + koff + acolsh);                   \
    } while (0)

    STAGEF(0, 0);
    for (int kt = 0; kt < 4; ++kt) {
        const int cur = kt & 1;
        if (kt < 3) {
            STAGEF(cur ^ 1, kt + 1);
            asm volatile("s_waitcnt vmcnt(3)\n\ts_barrier" ::: "memory");
        } else {
            asm volatile("s_waitcnt vmcnt(0)\n\ts_barrier" ::: "memory");
        }
        const ushort* As = smem + cur * 8192;
        const ushort* Bs = As + 4096;
        const int kcol = (l >> 4) * 8;
        bf16x8 aF[4], bF[2];
#pragma unroll
        for (int m = 0; m < 4; m++) aF[m] = *(const bf16x8*)&As[(wr * 64 + m * 16 + (l & 15)) * 32 + kcol];
#pragma unroll
        for (int n = 0; n < 2; n++) bF[n] = *(const bf16x8*)&Bs[(wc * 32 + n * 16 + (l & 15)) * 32 + kcol];
#pragma unroll
        for (int m = 0; m < 4; m++)
#pragma unroll
            for (int n = 0; n < 2; n++)
                acc[m][n] = __builtin_amdgcn_mfma_f32_16x16x32_bf16(aF[m], bF[n], acc[m][n], 0, 0, 0);
        asm volatile("s_waitcnt lgkmcnt(0)\n\ts_barrier" ::: "memory");
    }
#undef STAGEF
    __syncthreads();

    float* cw = (float*)smem + w * 2048;  // [64][32] fp32 per wave
#pragma unroll
    for (int m = 0; m < 4; m++)
#pragma unroll
        for (int n = 0; n < 2; n++) {
            int lr0 = m * 16 + (l >> 4) * 4;
            int lc = n * 16 + (l & 15);
#pragma unroll
            for (int j = 0; j < 4; j++) cw[(lr0 + j) * 32 + lc] = acc[m][n][j] + bias[n];
        }
#pragma unroll
    for (int r = 0; r < 8; r++) {
        int row = r * 8 + (l >> 3);
        int cf = (l & 7) * 4;
        float4 vv = *(const float4*)&cw[row * 32 + cf];
        int grow = m0 + wr * 64 + row;
        if (grow < N_NODES) *(float4*)&out[(size_t)grow * 64 + wc * 32 + cf] = vv;
    }
}

extern "C" void kernel_launch(void* const* d_in, const int* in_sizes, int n_in,
                              void* d_out, int out_size, void* d_ws, size_t ws_size,
                              hipStream_t stream) {
    const float* feat = (const float*)d_in[0];
    const int* src = (const int*)d_in[1];
    const int* dst = (const int*)d_in[2];
    const float* Wsf[3] = {(const float*)d_in[3], (const float*)d_in[7], (const float*)d_in[11]};
    const float* bsv[3] = {(const float*)d_in[4], (const float*)d_in[8], (const float*)d_in[12]};
    const float* Wnf[3] = {(const float*)d_in[5], (const float*)d_in[9], (const float*)d_in[13]};
    const float* bnv[3] = {(const float*)d_in[6], (const float*)d_in[10], (const float*)d_in[14]};
    const float* Wo = (const float*)d_in[15];
    const float* bo = (const float*)d_in[16];
    float* out = (float*)d_out;

    char* ws = (char*)d_ws;
    const size_t HB = (size_t)N_NODES * F * 2;  // 25.6 MB bf16
    ushort* h0 = (ushort*)ws;
    ushort* hA = (ushort*)(ws + HB);
    ushort* hB = (ushort*)(ws + 2 * HB);
    ushort* agg = (ushort*)(ws + 3 * HB);
    char* p = ws + 4 * HB;
    ushort* wt = (ushort*)p;       p += 6 * 16384 * 2;          // 6x [128][128] bf16
    ushort* wto = (ushort*)p;      p += 64 * 128 * 2;           // [64][128] bf16
    p = (char*)(((size_t)p + 255) & ~(size_t)255);
    int* deg = (int*)p;            p += (size_t)N_NODES * 4;
    float* inv = (float*)p;        p += (size_t)N_NODES * 4;
    int* rp = (int*)p;             p += (size_t)(N_NODES + 1) * 4 + 252;
    int* cnt = (int*)p;            p += (size_t)N_NODES * 4;
    int* col = (int*)p;            p += (size_t)N_EDGES * 4;
    int* blksum = (int*)p;

    const int nScanBlk = (N_NODES + 1023) / 1024;  // 98
    const int edgeBlk = (N_EDGES + 255) / 256;
    const int nodeBlk = (N_NODES + 255) / 256;

    // prep: convert features + weights; build CSR
    k_cvt<<<(N_NODES * F / 4 + 255) / 256, 256, 0, stream>>>((const float4*)feat, h0);
    k_wt<<<dim3(128, 6), 128, 0, stream>>>(Wsf[0], Wnf[0], Wsf[1], Wnf[1], Wsf[2], Wnf[2], wt);
    k_wto<<<64, 128, 0, stream>>>(Wo, wto);
    k_zero<<<nodeBlk, 256, 0, stream>>>(deg, cnt);
    k_hist<<<edgeBlk, 256, 0, stream>>>(dst, deg);
    k_scan1<<<nScanBlk, 256, 0, stream>>>(deg, rp, blksum);
    k_scan2<<<1, 128, 0, stream>>>(blksum, nScanBlk);
    k_scan3<<<nodeBlk, 256, 0, stream>>>(deg, rp, blksum, inv);
    k_fill<<<edgeBlk, 256, 0, stream>>>(src, dst, rp, cnt, col);

    const int aggBlk = (N_NODES * 32 + 255) / 256;   // 12500 (half-wave per node)
    const int gemmBlk = (N_NODES + 127) / 128;       // 782

    ushort* Wt0s = wt + 0 * 16384; ushort* Wt0n = wt + 1 * 16384;
    ushort* Wt1s = wt + 2 * 16384; ushort* Wt1n = wt + 3 * 16384;
    ushort* Wt2s = wt + 4 * 16384; ushort* Wt2n = wt + 5 * 16384;

    // layer 0
    k_agg<<<aggBlk, 256, 0, stream>>>(h0, rp, col, inv, agg);
    k_gemm<1><<<gemmBlk, 256, 0, stream>>>(h0, agg, Wt0s, Wt0n, bsv[0], bnv[0], hA);
    // layer 1
    k_agg<<<aggBlk, 256, 0, stream>>>(hA, rp, col, inv, agg);
    k_gemm<1><<<gemmBlk, 256, 0, stream>>>(hA, agg, Wt1s, Wt1n, bsv[1], bnv[1], hB);
    // layer 2
    k_agg<<<aggBlk, 256, 0, stream>>>(hB, rp, col, inv, agg);
    k_gemm<0><<<gemmBlk, 256, 0, stream>>>(hB, agg, Wt2s, Wt2n, bsv[2], bnv[2], hA);
    // final linear
    k_final<<<gemmBlk, 256, 0, stream>>>(hA, wto, bo, out);
}

// Round 7
// 244.593 us; speedup vs baseline: 2.6921x; 1.0066x over previous
//
#include <hip/hip_runtime.h>

#define N_NODES 100000
#define N_EDGES 600000
#define F 128
#define OUTD 64

typedef short bf16x8 __attribute__((ext_vector_type(8)));
typedef float f32x4 __attribute__((ext_vector_type(4)));

__device__ __forceinline__ unsigned short f2bf(float f) {
    union { float f; unsigned u; } v; v.f = f;
    unsigned u = v.u;
    return (unsigned short)((u + 0x7FFFu + ((u >> 16) & 1u)) >> 16);
}
__device__ __forceinline__ float bf2f(unsigned short s) {
    union { unsigned u; float f; } v; v.u = ((unsigned)s) << 16;
    return v.f;
}

__device__ __forceinline__ void async_copy16(void* lds, const void* g) {
    __builtin_amdgcn_global_load_lds((const __attribute__((address_space(1))) void*)g,
                                     (__attribute__((address_space(3))) void*)lds, 16, 0, 0);
}

// ---------------- feature convert fp32 -> bf16 ----------------
__global__ __launch_bounds__(256) void k_cvt(const float4* __restrict__ in, ushort* __restrict__ out) {
    int i = blockIdx.x * blockDim.x + threadIdx.x;  // 3.2M float4
    float4 v = in[i];
    ushort4 o;
    o.x = f2bf(v.x); o.y = f2bf(v.y); o.z = f2bf(v.z); o.w = f2bf(v.w);
    *(ushort4*)&out[i * 4] = o;
}

// ---------------- weight transpose+convert (layers 0,1): Wt[n][k] = bf16(W[k][n]) ----------------
__global__ __launch_bounds__(128) void k_wt(const float* __restrict__ w0, const float* __restrict__ w1,
                                            const float* __restrict__ w2, const float* __restrict__ w3,
                                            ushort* __restrict__ wt) {
    int which = blockIdx.y;
    const float* s = w0;
    if (which == 1) s = w1; else if (which == 2) s = w2; else if (which == 3) s = w3;
    int n = blockIdx.x, k = threadIdx.x;
    wt[which * 16384 + n * 128 + k] = f2bf(s[k * 128 + n]);
}

// ---------------- fused layer2+out weights: Wc = W2 @ Wo (fp32), stored bf16 [o][k] ----------------
// blocks 0..127: k = blockIdx.x, threads o=0..63. block 128: bias compose.
__global__ __launch_bounds__(64) void k_wfuse(const float* __restrict__ Ws2, const float* __restrict__ Wn2,
                                              const float* __restrict__ b2s, const float* __restrict__ b2n,
                                              const float* __restrict__ Wo, const float* __restrict__ bo,
                                              ushort* __restrict__ wcs, ushort* __restrict__ wcn,
                                              float* __restrict__ bc) {
    int o = threadIdx.x;
    if (blockIdx.x < 128) {
        int k = blockIdx.x;
        float sws = 0.f, swn = 0.f;
#pragma unroll 4
        for (int j = 0; j < 128; ++j) {
            float w = Wo[j * 64 + o];
            sws += Ws2[k * 128 + j] * w;
            swn += Wn2[k * 128 + j] * w;
        }
        wcs[o * 128 + k] = f2bf(sws);
        wcn[o * 128 + k] = f2bf(swn);
    } else {
        float s = bo[o];
#pragma unroll 4
        for (int j = 0; j < 128; ++j) s += (b2s[j] + b2n[j]) * Wo[j * 64 + o];
        bc[o] = s;
    }
}

// ---------------- CSR build ----------------
__global__ __launch_bounds__(256) void k_zero(int* __restrict__ a, int* __restrict__ b) {
    int i = blockIdx.x * blockDim.x + threadIdx.x;
    if (i < N_NODES) { a[i] = 0; b[i] = 0; }
}

__global__ __launch_bounds__(256) void k_hist(const int4* __restrict__ dst4, int* __restrict__ deg) {
    int e = blockIdx.x * blockDim.x + threadIdx.x;
    if (e < N_EDGES / 4) {
        int4 d = dst4[e];
        atomicAdd(&deg[d.x], 1);
        atomicAdd(&deg[d.y], 1);
        atomicAdd(&deg[d.z], 1);
        atomicAdd(&deg[d.w], 1);
    }
}

__global__ __launch_bounds__(256) void k_scan1(const int* __restrict__ deg, int* __restrict__ row_ptr,
                                               int* __restrict__ blksum) {
    __shared__ int sm[256];
    int t = threadIdx.x, b = blockIdx.x;
    int base = b * 1024 + t * 4;
    int v[4];
    int run = 0;
#pragma unroll
    for (int i = 0; i < 4; i++) {
        int idx = base + i;
        int d = (idx < N_NODES) ? deg[idx] : 0;
        run += d;
        v[i] = run;
    }
    sm[t] = run;
    __syncthreads();
    for (int off = 1; off < 256; off <<= 1) {
        int add = 0;
        if (t >= off) add = sm[t - off];
        __syncthreads();
        sm[t] += add;
        __syncthreads();
    }
    int excl = sm[t] - run;
#pragma unroll
    for (int i = 0; i < 4; i++) {
        int idx = base + i;
        if (idx < N_NODES) row_ptr[idx + 1] = excl + v[i];
    }
    if (t == 255) blksum[b] = sm[255];
}

__global__ __launch_bounds__(128) void k_scan2(int* __restrict__ blksum, int nblk) {
    __shared__ int sm[128];
    int t = threadIdx.x;
    int v = (t < nblk) ? blksum[t] : 0;
    sm[t] = v;
    __syncthreads();
    for (int off = 1; off < 128; off <<= 1) {
        int add = 0;
        if (t >= off) add = sm[t - off];
        __syncthreads();
        sm[t] += add;
        __syncthreads();
    }
    if (t < nblk) blksum[t] = sm[t] - v;  // exclusive
}

__global__ __launch_bounds__(256) void k_scan3(const int* __restrict__ deg, int* __restrict__ row_ptr,
                                               const int* __restrict__ blksum, float* __restrict__ inv_deg) {
    int i = blockIdx.x * blockDim.x + threadIdx.x;
    if (i == 0) row_ptr[0] = 0;
    if (i < N_NODES) {
        row_ptr[i + 1] += blksum[i >> 10];
        int d = deg[i];
        inv_deg[i] = 1.0f / (float)(d > 0 ? d : 1);
    }
}

__global__ __launch_bounds__(256) void k_fill(const int4* __restrict__ src4, const int4* __restrict__ dst4,
                                              const int* __restrict__ row_ptr, int* __restrict__ cnt,
                                              int* __restrict__ col) {
    int e = blockIdx.x * blockDim.x + threadIdx.x;
    if (e < N_EDGES / 4) {
        int4 d = dst4[e];
        int4 s = src4[e];
        int p0 = row_ptr[d.x] + atomicAdd(&cnt[d.x], 1);
        int p1 = row_ptr[d.y] + atomicAdd(&cnt[d.y], 1);
        int p2 = row_ptr[d.z] + atomicAdd(&cnt[d.z], 1);
        int p3 = row_ptr[d.w] + atomicAdd(&cnt[d.w], 1);
        col[p0] = s.x;
        col[p1] = s.y;
        col[p2] = s.z;
        col[p3] = s.w;
    }
}

// ---------------- aggregation: half-wave (32 lanes) per node, uint2 loads, 4x unroll ----------------
__device__ __forceinline__ void acc4(uint2 v, float& a, float& b, float& c, float& d) {
    a += bf2f((unsigned short)(v.x & 0xFFFFu));
    b += bf2f((unsigned short)(v.x >> 16));
    c += bf2f((unsigned short)(v.y & 0xFFFFu));
    d += bf2f((unsigned short)(v.y >> 16));
}

__global__ __launch_bounds__(256) void k_agg(const ushort* __restrict__ h, const int* __restrict__ row_ptr,
                                             const int* __restrict__ col, const float* __restrict__ inv_deg,
                                             ushort* __restrict__ out) {
    int gtid = blockIdx.x * blockDim.x + threadIdx.x;
    int node = gtid >> 5;            // one node per 32-lane half-wave
    int lane = threadIdx.x & 31;     // 4 bf16 per lane (8B)
    if (node >= N_NODES) return;
    int s = row_ptr[node], e = row_ptr[node + 1];
    const uint2* hp = (const uint2*)h;  // row stride = 32 uint2
    float ax0 = 0.f, ay0 = 0.f, az0 = 0.f, aw0 = 0.f;
    float ax1 = 0.f, ay1 = 0.f, az1 = 0.f, aw1 = 0.f;
    int p = s;
    for (; p + 4 <= e; p += 4) {
        int c0 = col[p + 0], c1 = col[p + 1], c2 = col[p + 2], c3 = col[p + 3];
        uint2 v0 = hp[(size_t)c0 * 32 + lane];
        uint2 v1 = hp[(size_t)c1 * 32 + lane];
        uint2 v2 = hp[(size_t)c2 * 32 + lane];
        uint2 v3 = hp[(size_t)c3 * 32 + lane];
        acc4(v0, ax0, ay0, az0, aw0);
        acc4(v1, ax1, ay1, az1, aw1);
        acc4(v2, ax0, ay0, az0, aw0);
        acc4(v3, ax1, ay1, az1, aw1);
    }
    for (; p < e; ++p) {
        int c = col[p];
        uint2 v = hp[(size_t)c * 32 + lane];
        acc4(v, ax0, ay0, az0, aw0);
    }
    float iv = inv_deg[node];
    float fx = (ax0 + ax1) * iv, fy = (ay0 + ay1) * iv;
    float fz = (az0 + az1) * iv, fw = (aw0 + aw1) * iv;
    uint2 o;
    o.x = (unsigned)f2bf(fx) | ((unsigned)f2bf(fy) << 16);
    o.y = (unsigned)f2bf(fz) | ((unsigned)f2bf(fw) << 16);
    ((uint2*)out)[(size_t)node * 32 + lane] = o;
}

// ---------------- MFMA fused dual GEMM, double-buffered with counted vmcnt ----------------
// BM=128, BN=128, K=256 (h||hn), BK=32. 4 waves 2x2, each 64x64 (4x4 frags of 16x16x32).
// Fence discipline: top barrier = counted vmcnt (prefetch in flight); end barrier drains
// lgkmcnt(0) so no ds_reads are in flight when next iter's DMA overwrites the buffer.
template <int RELU>
__global__ __launch_bounds__(256) void k_gemm(const ushort* __restrict__ h, const ushort* __restrict__ hn,
                                              const ushort* __restrict__ Wts, const ushort* __restrict__ Wtn,
                                              const float* __restrict__ bs, const float* __restrict__ bn,
                                              ushort* __restrict__ out) {
    __shared__ ushort smem[16384];  // 2 x (As[128][32] + Bs[128][32]); epilogue reuses
    const int t = threadIdx.x;
    const int w = t >> 6, l = t & 63;
    const int wr = w >> 1, wc = w & 1;
    const int m0 = blockIdx.x * 128;

    f32x4 acc[4][4];
#pragma unroll
    for (int m = 0; m < 4; m++)
#pragma unroll
        for (int n = 0; n < 4; n++) acc[m][n] = (f32x4){0.f, 0.f, 0.f, 0.f};

    float bias[4];
#pragma unroll
    for (int n = 0; n < 4; n++) {
        int gc = wc * 64 + n * 16 + (l & 15);
        bias[n] = bs[gc] + bn[gc];
    }

    const int arow = t >> 2;          // 0..63
    const int acolsh = (t & 3) * 8;   // short offset within 32-k row

#define STAGE(BUF, KT)                                                                            \
    do {                                                                                          \
        ushort* As_ = smem + (BUF) * 8192;                                                        \
        ushort* Bs_ = As_ + 4096;                                                                 \
        const ushort* Asrc = ((KT) < 4) ? h : hn;                                                 \
        const ushort* Bsrc = ((KT) < 4) ? Wts : Wtn;                                              \
        const int koff = ((KT) & 3) * 32;                                                         \
        _Pragma("unroll") for (int i = 0; i < 2; ++i) {                                           \
            int row = m0 + i * 64 + arow;                                                         \
            if (row > N_NODES - 1) row = N_NODES - 1;                                             \
            async_copy16(As_ + i * 2048 + w * 512, Asrc + (size_t)row * 128 + koff + acolsh);     \
            async_copy16(Bs_ + i * 2048 + w * 512,                                                \
                         Bsrc + (size_t)(i * 64 + arow) * 128 + koff + acolsh);                   \
        }                                                                                         \
    } while (0)

    STAGE(0, 0);
    for (int kt = 0; kt < 8; ++kt) {
        const int cur = kt & 1;
        if (kt < 7) {
            STAGE(cur ^ 1, kt + 1);
            asm volatile("s_waitcnt vmcnt(4)\n\ts_barrier" ::: "memory");
        } else {
            asm volatile("s_waitcnt vmcnt(0)\n\ts_barrier" ::: "memory");
        }
        const ushort* As = smem + cur * 8192;
        const ushort* Bs = As + 4096;
        const int kcol = (l >> 4) * 8;
        bf16x8 aF[4], bF[4];
#pragma unroll
        for (int m = 0; m < 4; m++) aF[m] = *(const bf16x8*)&As[(wr * 64 + m * 16 + (l & 15)) * 32 + kcol];
#pragma unroll
        for (int n = 0; n < 4; n++) bF[n] = *(const bf16x8*)&Bs[(wc * 64 + n * 16 + (l & 15)) * 32 + kcol];
#pragma unroll
        for (int m = 0; m < 4; m++)
#pragma unroll
            for (int n = 0; n < 4; n++)
                acc[m][n] = __builtin_amdgcn_mfma_f32_16x16x32_bf16(aF[m], bF[n], acc[m][n], 0, 0, 0);
        asm volatile("s_waitcnt lgkmcnt(0)\n\ts_barrier" ::: "memory");
    }
#undef STAGE
    __syncthreads();  // full drain; repurpose smem for epilogue

    ushort* cw = smem + w * 4096;  // [64][64] bf16 per wave
#pragma unroll
    for (int m = 0; m < 4; m++)
#pragma unroll
        for (int n = 0; n < 4; n++) {
            int lr0 = m * 16 + (l >> 4) * 4;
            int lc = n * 16 + (l & 15);
#pragma unroll
            for (int j = 0; j < 4; j++) {
                float v = acc[m][n][j] + bias[n];
                if (RELU) v = fmaxf(v, 0.f);
                cw[(lr0 + j) * 64 + lc] = f2bf(v);
            }
        }
#pragma unroll
    for (int r = 0; r < 8; r++) {
        int row = r * 8 + (l >> 3);
        int cs = (l & 7) * 8;
        bf16x8 vv = *(const bf16x8*)&cw[row * 64 + cs];
        int grow = m0 + wr * 64 + row;
        if (grow < N_NODES) *(bf16x8*)&out[(size_t)grow * 128 + wc * 64 + cs] = vv;
    }
}

// ---------------- fused layer2+final: out(fp32) = h@Wcs + hn@Wcn + bc ----------------
// BM=128, BN=64, K=256 (h||hn), BK=32. 4 waves 2x2, each 64x32 (4x2 frags).
__global__ __launch_bounds__(256) void k_gemm_out(const ushort* __restrict__ h, const ushort* __restrict__ hn,
                                                  const ushort* __restrict__ Wcs, const ushort* __restrict__ Wcn,
                                                  const float* __restrict__ bc, float* __restrict__ out) {
    __shared__ ushort smem[16384];  // staging 2 x (As 4096 + Bs 2048) = 12288; epilogue 16384
    const int t = threadIdx.x;
    const int w = t >> 6, l = t & 63;
    const int wr = w >> 1, wc = w & 1;
    const int m0 = blockIdx.x * 128;

    f32x4 acc[4][2];
#pragma unroll
    for (int m = 0; m < 4; m++)
#pragma unroll
        for (int n = 0; n < 2; n++) acc[m][n] = (f32x4){0.f, 0.f, 0.f, 0.f};

    float bias[2];
#pragma unroll
    for (int n = 0; n < 2; n++) bias[n] = bc[wc * 32 + n * 16 + (l & 15)];

    const int arow = t >> 2;
    const int acolsh = (t & 3) * 8;

#define STAGEO(BUF, KT)                                                                          \
    do {                                                                                         \
        ushort* As_ = smem + (BUF) * 6144;                                                       \
        ushort* Bs_ = As_ + 4096;                                                                \
        const ushort* Asrc = ((KT) < 4) ? h : hn;                                                \
        const ushort* Bsrc = ((KT) < 4) ? Wcs : Wcn;                                             \
        const int koff = ((KT) & 3) * 32;                                                        \
        _Pragma("unroll") for (int i = 0; i < 2; ++i) {                                          \
            int row = m0 + i * 64 + arow;                                                        \
            if (row > N_NODES - 1) row = N_NODES - 1;                                            \
            async_copy16(As_ + i * 2048 + w * 512, Asrc + (size_t)row * 128 + koff + acolsh);    \
        }                                                                                        \
        async_copy16(Bs_ + w * 512, Bsrc + (size_t)arow * 128 + koff + acolsh);                  \
    } while (0)

    STAGEO(0, 0);
    for (int kt = 0; kt < 8; ++kt) {
        const int cur = kt & 1;
        if (kt < 7) {
            STAGEO(cur ^ 1, kt + 1);
            asm volatile("s_waitcnt vmcnt(3)\n\ts_barrier" ::: "memory");
        } else {
            asm volatile("s_waitcnt vmcnt(0)\n\ts_barrier" ::: "memory");
        }
        const ushort* As = smem + cur * 6144;
        const ushort* Bs = As + 4096;
        const int kcol = (l >> 4) * 8;
        bf16x8 aF[4], bF[2];
#pragma unroll
        for (int m = 0; m < 4; m++) aF[m] = *(const bf16x8*)&As[(wr * 64 + m * 16 + (l & 15)) * 32 + kcol];
#pragma unroll
        for (int n = 0; n < 2; n++) bF[n] = *(const bf16x8*)&Bs[(wc * 32 + n * 16 + (l & 15)) * 32 + kcol];
#pragma unroll
        for (int m = 0; m < 4; m++)
#pragma unroll
            for (int n = 0; n < 2; n++)
                acc[m][n] = __builtin_amdgcn_mfma_f32_16x16x32_bf16(aF[m], bF[n], acc[m][n], 0, 0, 0);
        asm volatile("s_waitcnt lgkmcnt(0)\n\ts_barrier" ::: "memory");
    }
#undef STAGEO
    __syncthreads();

    float* cw = (float*)smem + w * 2048;  // [64][32] fp32 per wave
#pragma unroll
    for (int m = 0; m < 4; m++)
#pragma unroll
        for (int n = 0; n < 2; n++) {
            int lr0 = m * 16 + (l >> 4) * 4;
            int lc = n * 16 + (l & 15);
#pragma unroll
            for (int j = 0; j < 4; j++) cw[(lr0 + j) * 32 + lc] = acc[m][n][j] + bias[n];
        }
#pragma unroll
    for (int r = 0; r < 8; r++) {
        int row = r * 8 + (l >> 3);
        int cf = (l & 7) * 4;
        float4 vv = *(const float4*)&cw[row * 32 + cf];
        int grow = m0 + wr * 64 + row;
        if (grow < N_NODES) *(float4*)&out[(size_t)grow * 64 + wc * 32 + cf] = vv;
    }
}

extern "C" void kernel_launch(void* const* d_in, const int* in_sizes, int n_in,
                              void* d_out, int out_size, void* d_ws, size_t ws_size,
                              hipStream_t stream) {
    const float* feat = (const float*)d_in[0];
    const int* src = (const int*)d_in[1];
    const int* dst = (const int*)d_in[2];
    const float* Wsf[3] = {(const float*)d_in[3], (const float*)d_in[7], (const float*)d_in[11]};
    const float* bsv[3] = {(const float*)d_in[4], (const float*)d_in[8], (const float*)d_in[12]};
    const float* Wnf[3] = {(const float*)d_in[5], (const float*)d_in[9], (const float*)d_in[13]};
    const float* bnv[3] = {(const float*)d_in[6], (const float*)d_in[10], (const float*)d_in[14]};
    const float* Wo = (const float*)d_in[15];
    const float* bo = (const float*)d_in[16];
    float* out = (float*)d_out;

    char* ws = (char*)d_ws;
    const size_t HB = (size_t)N_NODES * F * 2;  // 25.6 MB bf16
    ushort* h0 = (ushort*)ws;
    ushort* hA = (ushort*)(ws + HB);
    ushort* hB = (ushort*)(ws + 2 * HB);
    ushort* agg = (ushort*)(ws + 3 * HB);
    char* p = ws + 4 * HB;
    ushort* wt = (ushort*)p;       p += 4 * 16384 * 2;          // 4x [128][128] bf16 (layers 0,1)
    ushort* wcs = (ushort*)p;      p += 64 * 128 * 2;           // composed [64][128] bf16
    ushort* wcn = (ushort*)p;      p += 64 * 128 * 2;
    p = (char*)(((size_t)p + 255) & ~(size_t)255);
    float* bc = (float*)p;         p += 64 * 4 + 192;           // composed bias, keep 256B align
    int* deg = (int*)p;            p += (size_t)N_NODES * 4;
    float* inv = (float*)p;        p += (size_t)N_NODES * 4;
    int* rp = (int*)p;             p += (size_t)(N_NODES + 1) * 4 + 252;
    int* cnt = (int*)p;            p += (size_t)N_NODES * 4;
    int* col = (int*)p;            p += (size_t)N_EDGES * 4;
    int* blksum = (int*)p;

    const int nScanBlk = (N_NODES + 1023) / 1024;  // 98
    const int edge4Blk = (N_EDGES / 4 + 255) / 256;  // 586
    const int nodeBlk = (N_NODES + 255) / 256;

    // prep: convert features + weights; build CSR
    k_cvt<<<(N_NODES * F / 4 + 255) / 256, 256, 0, stream>>>((const float4*)feat, h0);
    k_wt<<<dim3(128, 4), 128, 0, stream>>>(Wsf[0], Wnf[0], Wsf[1], Wnf[1], wt);
    k_wfuse<<<129, 64, 0, stream>>>(Wsf[2], Wnf[2], bsv[2], bnv[2], Wo, bo, wcs, wcn, bc);
    k_zero<<<nodeBlk, 256, 0, stream>>>(deg, cnt);
    k_hist<<<edge4Blk, 256, 0, stream>>>((const int4*)dst, deg);
    k_scan1<<<nScanBlk, 256, 0, stream>>>(deg, rp, blksum);
    k_scan2<<<1, 128, 0, stream>>>(blksum, nScanBlk);
    k_scan3<<<nodeBlk, 256, 0, stream>>>(deg, rp, blksum, inv);
    k_fill<<<edge4Blk, 256, 0, stream>>>((const int4*)src, (const int4*)dst, rp, cnt, col);

    const int aggBlk = (N_NODES * 32 + 255) / 256;   // 12500 (half-wave per node)
    const int gemmBlk = (N_NODES + 127) / 128;       // 782

    ushort* Wt0s = wt + 0 * 16384; ushort* Wt0n = wt + 1 * 16384;
    ushort* Wt1s = wt + 2 * 16384; ushort* Wt1n = wt + 3 * 16384;

    // layer 0
    k_agg<<<aggBlk, 256, 0, stream>>>(h0, rp, col, inv, agg);
    k_gemm<1><<<gemmBlk, 256, 0, stream>>>(h0, agg, Wt0s, Wt0n, bsv[0], bnv[0], hA);
    // layer 1
    k_agg<<<aggBlk, 256, 0, stream>>>(hA, rp, col, inv, agg);
    k_gemm<1><<<gemmBlk, 256, 0, stream>>>(hA, agg, Wt1s, Wt1n, bsv[1], bnv[1], hB);
    // layer 2 fused with final linear (no ReLU between them; algebraic weight composition)
    k_agg<<<aggBlk, 256, 0, stream>>>(hB, rp, col, inv, agg);
    k_gemm_out<<<gemmBlk, 256, 0, stream>>>(hB, agg, wcs, wcn, bc, out);
}

// Round 9
// 208.224 us; speedup vs baseline: 3.1623x; 1.1747x over previous
//
#include <hip/hip_runtime.h>

#define N_NODES 100000
#define N_EDGES 600000
#define F 128
#define OUTD 64

typedef short bf16x8 __attribute__((ext_vector_type(8)));
typedef float f32x4 __attribute__((ext_vector_type(4)));

__device__ __forceinline__ unsigned short f2bf(float f) {
    union { float f; unsigned u; } v; v.f = f;
    unsigned u = v.u;
    return (unsigned short)((u + 0x7FFFu + ((u >> 16) & 1u)) >> 16);
}
__device__ __forceinline__ float bf2f(unsigned short s) {
    union { unsigned u; float f; } v; v.u = ((unsigned)s) << 16;
    return v.f;
}

__device__ __forceinline__ void async_copy16(void* lds, const void* g) {
    __builtin_amdgcn_global_load_lds((const __attribute__((address_space(1))) void*)g,
                                     (__attribute__((address_space(3))) void*)lds, 16, 0, 0);
}

// ---------------- feature convert fp32 -> bf16 ----------------
__global__ __launch_bounds__(256) void k_cvt(const float4* __restrict__ in, ushort* __restrict__ out) {
    int i = blockIdx.x * blockDim.x + threadIdx.x;  // 3.2M float4
    float4 v = in[i];
    ushort4 o;
    o.x = f2bf(v.x); o.y = f2bf(v.y); o.z = f2bf(v.z); o.w = f2bf(v.w);
    *(ushort4*)&out[i * 4] = o;
}

// ---------------- weight transpose+convert (layers 0,1): Wt[n][k] = bf16(W[k][n]) ----------------
__global__ __launch_bounds__(128) void k_wt(const float* __restrict__ w0, const float* __restrict__ w1,
                                            const float* __restrict__ w2, const float* __restrict__ w3,
                                            ushort* __restrict__ wt) {
    int which = blockIdx.y;
    const float* s = w0;
    if (which == 1) s = w1; else if (which == 2) s = w2; else if (which == 3) s = w3;
    int n = blockIdx.x, k = threadIdx.x;
    wt[which * 16384 + n * 128 + k] = f2bf(s[k * 128 + n]);
}

// ---------------- fused layer2+out weights: Wc = W2 @ Wo (fp32), stored bf16 [o][k] ----------------
__global__ __launch_bounds__(64) void k_wfuse(const float* __restrict__ Ws2, const float* __restrict__ Wn2,
                                              const float* __restrict__ b2s, const float* __restrict__ b2n,
                                              const float* __restrict__ Wo, const float* __restrict__ bo,
                                              ushort* __restrict__ wcs, ushort* __restrict__ wcn,
                                              float* __restrict__ bc) {
    int o = threadIdx.x;
    if (blockIdx.x < 128) {
        int k = blockIdx.x;
        float sws = 0.f, swn = 0.f;
#pragma unroll 4
        for (int j = 0; j < 128; ++j) {
            float w = Wo[j * 64 + o];
            sws += Ws2[k * 128 + j] * w;
            swn += Wn2[k * 128 + j] * w;
        }
        wcs[o * 128 + k] = f2bf(sws);
        wcn[o * 128 + k] = f2bf(swn);
    } else {
        float s = bo[o];
#pragma unroll 4
        for (int j = 0; j < 128; ++j) s += (b2s[j] + b2n[j]) * Wo[j * 64 + o];
        bc[o] = s;
    }
}

// ---------------- CSR build (atomic-free fill via edge ranks) ----------------
__global__ __launch_bounds__(256) void k_zero(int* __restrict__ a) {
    int i = blockIdx.x * blockDim.x + threadIdx.x;
    if (i < N_NODES) a[i] = 0;
}

// ord[e] = rank of edge e within its destination; deg accumulates counts.
__global__ __launch_bounds__(256) void k_hist(const int* __restrict__ dst, int* __restrict__ deg,
                                              int* __restrict__ ord) {
    int e = blockIdx.x * blockDim.x + threadIdx.x;
    if (e < N_EDGES) ord[e] = atomicAdd(&deg[dst[e]], 1);
}

__global__ __launch_bounds__(256) void k_scan1(const int* __restrict__ deg, int* __restrict__ row_ptr,
                                               int* __restrict__ blksum) {
    __shared__ int sm[256];
    int t = threadIdx.x, b = blockIdx.x;
    int base = b * 1024 + t * 4;
    int v[4];
    int run = 0;
#pragma unroll
    for (int i = 0; i < 4; i++) {
        int idx = base + i;
        int d = (idx < N_NODES) ? deg[idx] : 0;
        run += d;
        v[i] = run;
    }
    sm[t] = run;
    __syncthreads();
    for (int off = 1; off < 256; off <<= 1) {
        int add = 0;
        if (t >= off) add = sm[t - off];
        __syncthreads();
        sm[t] += add;
        __syncthreads();
    }
    int excl = sm[t] - run;
#pragma unroll
    for (int i = 0; i < 4; i++) {
        int idx = base + i;
        if (idx < N_NODES) row_ptr[idx + 1] = excl + v[i];
    }
    if (t == 255) blksum[b] = sm[255];
}

__global__ __launch_bounds__(128) void k_scan2(int* __restrict__ blksum, int nblk) {
    __shared__ int sm[128];
    int t = threadIdx.x;
    int v = (t < nblk) ? blksum[t] : 0;
    sm[t] = v;
    __syncthreads();
    for (int off = 1; off < 128; off <<= 1) {
        int add = 0;
        if (t >= off) add = sm[t - off];
        __syncthreads();
        sm[t] += add;
        __syncthreads();
    }
    if (t < nblk) blksum[t] = sm[t] - v;  // exclusive
}

__global__ __launch_bounds__(256) void k_scan3(const int* __restrict__ deg, int* __restrict__ row_ptr,
                                               const int* __restrict__ blksum, float* __restrict__ inv_deg) {
    int i = blockIdx.x * blockDim.x + threadIdx.x;
    if (i == 0) row_ptr[0] = 0;
    if (i < N_NODES) {
        row_ptr[i + 1] += blksum[i >> 10];
        int d = deg[i];
        inv_deg[i] = 1.0f / (float)(d > 0 ? d : 1);
    }
}

// no atomics: position = row_ptr[dst] + precomputed rank. Scattered store is fire-and-forget.
__global__ __launch_bounds__(256) void k_fill(const int* __restrict__ src, const int* __restrict__ dst,
                                              const int* __restrict__ row_ptr, const int* __restrict__ ord,
                                              int* __restrict__ col) {
    int e = blockIdx.x * blockDim.x + threadIdx.x;
    if (e < N_EDGES) {
        int d = dst[e];
        col[row_ptr[d] + ord[e]] = src[e];
    }
}

// ---------------- aggregation: quarter-wave (16 lanes) per node, uint4 loads, 4x unroll ----------------
// row = 128 bf16 = 256 B = 16 uint4; lane 0..15 covers it at stride 16 (r8 bug: stride was 8).
__device__ __forceinline__ void acc8(uint4 v, float* A) {
    A[0] += bf2f((unsigned short)(v.x & 0xFFFFu));
    A[1] += bf2f((unsigned short)(v.x >> 16));
    A[2] += bf2f((unsigned short)(v.y & 0xFFFFu));
    A[3] += bf2f((unsigned short)(v.y >> 16));
    A[4] += bf2f((unsigned short)(v.z & 0xFFFFu));
    A[5] += bf2f((unsigned short)(v.z >> 16));
    A[6] += bf2f((unsigned short)(v.w & 0xFFFFu));
    A[7] += bf2f((unsigned short)(v.w >> 16));
}

__global__ __launch_bounds__(256) void k_agg(const ushort* __restrict__ h, const int* __restrict__ row_ptr,
                                             const int* __restrict__ col, const float* __restrict__ inv_deg,
                                             ushort* __restrict__ out) {
    int gtid = blockIdx.x * blockDim.x + threadIdx.x;
    int node = gtid >> 4;            // one node per 16-lane quarter-wave
    int lane = threadIdx.x & 15;     // 8 bf16 per lane (16B)
    if (node >= N_NODES) return;
    int s = row_ptr[node], e = row_ptr[node + 1];
    const uint4* hp = (const uint4*)h;  // row stride = 16 uint4
    float A[8] = {0.f, 0.f, 0.f, 0.f, 0.f, 0.f, 0.f, 0.f};
    float B[8] = {0.f, 0.f, 0.f, 0.f, 0.f, 0.f, 0.f, 0.f};
    int p = s;
    for (; p + 4 <= e; p += 4) {
        int c0 = col[p + 0], c1 = col[p + 1], c2 = col[p + 2], c3 = col[p + 3];
        uint4 v0 = hp[(size_t)c0 * 16 + lane];
        uint4 v1 = hp[(size_t)c1 * 16 + lane];
        uint4 v2 = hp[(size_t)c2 * 16 + lane];
        uint4 v3 = hp[(size_t)c3 * 16 + lane];
        acc8(v0, A); acc8(v1, B); acc8(v2, A); acc8(v3, B);
    }
    for (; p < e; ++p) {
        uint4 v = hp[(size_t)col[p] * 16 + lane];
        acc8(v, A);
    }
    float iv = inv_deg[node];
    uint4 o;
    o.x = (unsigned)f2bf((A[0] + B[0]) * iv) | ((unsigned)f2bf((A[1] + B[1]) * iv) << 16);
    o.y = (unsigned)f2bf((A[2] + B[2]) * iv) | ((unsigned)f2bf((A[3] + B[3]) * iv) << 16);
    o.z = (unsigned)f2bf((A[4] + B[4]) * iv) | ((unsigned)f2bf((A[5] + B[5]) * iv) << 16);
    o.w = (unsigned)f2bf((A[6] + B[6]) * iv) | ((unsigned)f2bf((A[7] + B[7]) * iv) << 16);
    ((uint4*)out)[(size_t)node * 16 + lane] = o;
}

// ---------------- MFMA fused dual GEMM, double-buffered with counted vmcnt ----------------
template <int RELU>
__global__ __launch_bounds__(256) void k_gemm(const ushort* __restrict__ h, const ushort* __restrict__ hn,
                                              const ushort* __restrict__ Wts, const ushort* __restrict__ Wtn,
                                              const float* __restrict__ bs, const float* __restrict__ bn,
                                              ushort* __restrict__ out) {
    __shared__ ushort smem[16384];  // 2 x (As[128][32] + Bs[128][32]); epilogue reuses
    const int t = threadIdx.x;
    const int w = t >> 6, l = t & 63;
    const int wr = w >> 1, wc = w & 1;
    const int m0 = blockIdx.x * 128;

    f32x4 acc[4][4];
#pragma unroll
    for (int m = 0; m < 4; m++)
#pragma unroll
        for (int n = 0; n < 4; n++) acc[m][n] = (f32x4){0.f, 0.f, 0.f, 0.f};

    float bias[4];
#pragma unroll
    for (int n = 0; n < 4; n++) {
        int gc = wc * 64 + n * 16 + (l & 15);
        bias[n] = bs[gc] + bn[gc];
    }

    const int arow = t >> 2;          // 0..63
    const int acolsh = (t & 3) * 8;   // short offset within 32-k row

#define STAGE(BUF, KT)                                                                            \
    do {                                                                                          \
        ushort* As_ = smem + (BUF) * 8192;                                                        \
        ushort* Bs_ = As_ + 4096;                                                                 \
        const ushort* Asrc = ((KT) < 4) ? h : hn;                                                 \
        const ushort* Bsrc = ((KT) < 4) ? Wts : Wtn;                                              \
        const int koff = ((KT) & 3) * 32;                                                         \
        _Pragma("unroll") for (int i = 0; i < 2; ++i) {                                           \
            int row = m0 + i * 64 + arow;                                                         \
            if (row > N_NODES - 1) row = N_NODES - 1;                                             \
            async_copy16(As_ + i * 2048 + w * 512, Asrc + (size_t)row * 128 + koff + acolsh);     \
            async_copy16(Bs_ + i * 2048 + w * 512,                                                \
                         Bsrc + (size_t)(i * 64 + arow) * 128 + koff + acolsh);                   \
        }                                                                                         \
    } while (0)

    STAGE(0, 0);
    for (int kt = 0; kt < 8; ++kt) {
        const int cur = kt & 1;
        if (kt < 7) {
            STAGE(cur ^ 1, kt + 1);
            asm volatile("s_waitcnt vmcnt(4)\n\ts_barrier" ::: "memory");
        } else {
            asm volatile("s_waitcnt vmcnt(0)\n\ts_barrier" ::: "memory");
        }
        const ushort* As = smem + cur * 8192;
        const ushort* Bs = As + 4096;
        const int kcol = (l >> 4) * 8;
        bf16x8 aF[4], bF[4];
#pragma unroll
        for (int m = 0; m < 4; m++) aF[m] = *(const bf16x8*)&As[(wr * 64 + m * 16 + (l & 15)) * 32 + kcol];
#pragma unroll
        for (int n = 0; n < 4; n++) bF[n] = *(const bf16x8*)&Bs[(wc * 64 + n * 16 + (l & 15)) * 32 + kcol];
#pragma unroll
        for (int m = 0; m < 4; m++)
#pragma unroll
            for (int n = 0; n < 4; n++)
                acc[m][n] = __builtin_amdgcn_mfma_f32_16x16x32_bf16(aF[m], bF[n], acc[m][n], 0, 0, 0);
        asm volatile("s_waitcnt lgkmcnt(0)\n\ts_barrier" ::: "memory");
    }
#undef STAGE
    __syncthreads();  // full drain; repurpose smem for epilogue

    ushort* cw = smem + w * 4096;  // [64][64] bf16 per wave
#pragma unroll
    for (int m = 0; m < 4; m++)
#pragma unroll
        for (int n = 0; n < 4; n++) {
            int lr0 = m * 16 + (l >> 4) * 4;
            int lc = n * 16 + (l & 15);
#pragma unroll
            for (int j = 0; j < 4; j++) {
                float v = acc[m][n][j] + bias[n];
                if (RELU) v = fmaxf(v, 0.f);
                cw[(lr0 + j) * 64 + lc] = f2bf(v);
            }
        }
#pragma unroll
    for (int r = 0; r < 8; r++) {
        int row = r * 8 + (l >> 3);
        int cs = (l & 7) * 8;
        bf16x8 vv = *(const bf16x8*)&cw[row * 64 + cs];
        int grow = m0 + wr * 64 + row;
        if (grow < N_NODES) *(bf16x8*)&out[(size_t)grow * 128 + wc * 64 + cs] = vv;
    }
}

// ---------------- fused layer2+final: out(fp32) = h@Wcs + hn@Wcn + bc ----------------
__global__ __launch_bounds__(256) void k_gemm_out(const ushort* __restrict__ h, const ushort* __restrict__ hn,
                                                  const ushort* __restrict__ Wcs, const ushort* __restrict__ Wcn,
                                                  const float* __restrict__ bc, float* __restrict__ out) {
    __shared__ ushort smem[16384];
    const int t = threadIdx.x;
    const int w = t >> 6, l = t & 63;
    const int wr = w >> 1, wc = w & 1;
    const int m0 = blockIdx.x * 128;

    f32x4 acc[4][2];
#pragma unroll
    for (int m = 0; m < 4; m++)
#pragma unroll
        for (int n = 0; n < 2; n++) acc[m][n] = (f32x4){0.f, 0.f, 0.f, 0.f};

    float bias[2];
#pragma unroll
    for (int n = 0; n < 2; n++) bias[n] = bc[wc * 32 + n * 16 + (l & 15)];

    const int arow = t >> 2;
    const int acolsh = (t & 3) * 8;

#define STAGEO(BUF, KT)                                                                          \
    do {                                                                                         \
        ushort* As_ = smem + (BUF) * 6144;                                                       \
        ushort* Bs_ = As_ + 4096;                                                                \
        const ushort* Asrc = ((KT) < 4) ? h : hn;                                                \
        const ushort* Bsrc = ((KT) < 4) ? Wcs : Wcn;                                             \
        const int koff = ((KT) & 3) * 32;                                                        \
        _Pragma("unroll") for (int i = 0; i < 2; ++i) {                                          \
            int row = m0 + i * 64 + arow;                                                        \
            if (row > N_NODES - 1) row = N_NODES - 1;                                            \
            async_copy16(As_ + i * 2048 + w * 512, Asrc + (size_t)row * 128 + koff + acolsh);    \
        }                                                                                        \
        async_copy16(Bs_ + w * 512, Bsrc + (size_t)arow * 128 + koff + acolsh);                  \
    } while (0)

    STAGEO(0, 0);
    for (int kt = 0; kt < 8; ++kt) {
        const int cur = kt & 1;
        if (kt < 7) {
            STAGEO(cur ^ 1, kt + 1);
            asm volatile("s_waitcnt vmcnt(3)\n\ts_barrier" ::: "memory");
        } else {
            asm volatile("s_waitcnt vmcnt(0)\n\ts_barrier" ::: "memory");
        }
        const ushort* As = smem + cur * 6144;
        const ushort* Bs = As + 4096;
        const int kcol = (l >> 4) * 8;
        bf16x8 aF[4], bF[2];
#pragma unroll
        for (int m = 0; m < 4; m++) aF[m] = *(const bf16x8*)&As[(wr * 64 + m * 16 + (l & 15)) * 32 + kcol];
#pragma unroll
        for (int n = 0; n < 2; n++) bF[n] = *(const bf16x8*)&Bs[(wc * 32 + n * 16 + (l & 15)) * 32 + kcol];
#pragma unroll
        for (int m = 0; m < 4; m++)
#pragma unroll
            for (int n = 0; n < 2; n++)
                acc[m][n] = __builtin_amdgcn_mfma_f32_16x16x32_bf16(aF[m], bF[n], acc[m][n], 0, 0, 0);
        asm volatile("s_waitcnt lgkmcnt(0)\n\ts_barrier" ::: "memory");
    }
#undef STAGEO
    __syncthreads();

    float* cw = (float*)smem + w * 2048;  // [64][32] fp32 per wave
#pragma unroll
    for (int m = 0; m < 4; m++)
#pragma unroll
        for (int n = 0; n < 2; n++) {
            int lr0 = m * 16 + (l >> 4) * 4;
            int lc = n * 16 + (l & 15);
#pragma unroll
            for (int j = 0; j < 4; j++) cw[(lr0 + j) * 32 + lc] = acc[m][n][j] + bias[n];
        }
#pragma unroll
    for (int r = 0; r < 8; r++) {
        int row = r * 8 + (l >> 3);
        int cf = (l & 7) * 4;
        float4 vv = *(const float4*)&cw[row * 32 + cf];
        int grow = m0 + wr * 64 + row;
        if (grow < N_NODES) *(float4*)&out[(size_t)grow * 64 + wc * 32 + cf] = vv;
    }
}

extern "C" void kernel_launch(void* const* d_in, const int* in_sizes, int n_in,
                              void* d_out, int out_size, void* d_ws, size_t ws_size,
                              hipStream_t stream) {
    const float* feat = (const float*)d_in[0];
    const int* src = (const int*)d_in[1];
    const int* dst = (const int*)d_in[2];
    const float* Wsf[3] = {(const float*)d_in[3], (const float*)d_in[7], (const float*)d_in[11]};
    const float* bsv[3] = {(const float*)d_in[4], (const float*)d_in[8], (const float*)d_in[12]};
    const float* Wnf[3] = {(const float*)d_in[5], (const float*)d_in[9], (const float*)d_in[13]};
    const float* bnv[3] = {(const float*)d_in[6], (const float*)d_in[10], (const float*)d_in[14]};
    const float* Wo = (const float*)d_in[15];
    const float* bo = (const float*)d_in[16];
    float* out = (float*)d_out;

    char* ws = (char*)d_ws;
    const size_t HB = (size_t)N_NODES * F * 2;  // 25.6 MB bf16
    ushort* h0 = (ushort*)ws;
    ushort* hA = (ushort*)(ws + HB);
    ushort* hB = (ushort*)(ws + 2 * HB);
    ushort* agg = (ushort*)(ws + 3 * HB);
    char* p = ws + 4 * HB;
    ushort* wt = (ushort*)p;       p += 4 * 16384 * 2;          // 4x [128][128] bf16 (layers 0,1)
    ushort* wcs = (ushort*)p;      p += 64 * 128 * 2;           // composed [64][128] bf16
    ushort* wcn = (ushort*)p;      p += 64 * 128 * 2;
    p = (char*)(((size_t)p + 255) & ~(size_t)255);
    float* bc = (float*)p;         p += 64 * 4 + 192;           // composed bias, keep 256B align
    int* deg = (int*)p;            p += (size_t)N_NODES * 4;
    float* inv = (float*)p;        p += (size_t)N_NODES * 4;
    int* rp = (int*)p;             p += (size_t)(N_NODES + 1) * 4 + 252;
    int* ord = (int*)p;            p += (size_t)N_EDGES * 4;
    int* col = (int*)p;            p += (size_t)N_EDGES * 4;
    int* blksum = (int*)p;

    const int nScanBlk = (N_NODES + 1023) / 1024;   // 98
    const int edgeBlk = (N_EDGES + 255) / 256;      // 2344
    const int nodeBlk = (N_NODES + 255) / 256;

    // prep: convert features + weights; build CSR (atomic-free fill)
    k_cvt<<<(N_NODES * F / 4 + 255) / 256, 256, 0, stream>>>((const float4*)feat, h0);
    k_wt<<<dim3(128, 4), 128, 0, stream>>>(Wsf[0], Wnf[0], Wsf[1], Wnf[1], wt);
    k_wfuse<<<129, 64, 0, stream>>>(Wsf[2], Wnf[2], bsv[2], bnv[2], Wo, bo, wcs, wcn, bc);
    k_zero<<<nodeBlk, 256, 0, stream>>>(deg);
    k_hist<<<edgeBlk, 256, 0, stream>>>(dst, deg, ord);
    k_scan1<<<nScanBlk, 256, 0, stream>>>(deg, rp, blksum);
    k_scan2<<<1, 128, 0, stream>>>(blksum, nScanBlk);
    k_scan3<<<nodeBlk, 256, 0, stream>>>(deg, rp, blksum, inv);
    k_fill<<<edgeBlk, 256, 0, stream>>>(src, dst, rp, ord, col);

    const int aggBlk = (N_NODES * 16 + 255) / 256;   // 6250 (quarter-wave per node)
    const int gemmBlk = (N_NODES + 127) / 128;       // 782

    ushort* Wt0s = wt + 0 * 16384; ushort* Wt0n = wt + 1 * 16384;
    ushort* Wt1s = wt + 2 * 16384; ushort* Wt1n = wt + 3 * 16384;

    // layer 0
    k_agg<<<aggBlk, 256, 0, stream>>>(h0, rp, col, inv, agg);
    k_gemm<1><<<gemmBlk, 256, 0, stream>>>(h0, agg, Wt0s, Wt0n, bsv[0], bnv[0], hA);
    // layer 1
    k_agg<<<aggBlk, 256, 0, stream>>>(hA, rp, col, inv, agg);
    k_gemm<1><<<gemmBlk, 256, 0, stream>>>(hA, agg, Wt1s, Wt1n, bsv[1], bnv[1], hB);
    // layer 2 fused with final linear
    k_agg<<<aggBlk, 256, 0, stream>>>(hB, rp, col, inv, agg);
    k_gemm_out<<<gemmBlk, 256, 0, stream>>>(hB, agg, wcs, wcn, bc, out);
}